// Round 3
// baseline (9916.371 us; speedup 1.0000x reference)
//
#include <hip/hip_runtime.h>
#include <hip/hip_bf16.h>

// Problem dims
constexpr int B_  = 16;
constexpr int N_  = 64;     // stations
constexpr int T_  = 168;    // seq
constexpr int F_  = 8;      // raw features
constexpr int D_  = 248;    // gcn dim
constexpr int E_  = 256;    // dmodel
constexpr int H_  = 8;      // heads
constexpr int DH_ = 32;     // head dim
constexpr int FF_ = 1024;   // ff dim
constexpr int BN_ = B_ * N_;           // 1024
constexpr long ROWS_ = (long)BN_ * T_; // 172032
constexpr int NT_ = N_ * T_;           // 10752 (rows per batch)

// ---------------------------------------------------------------------------
// Kernel 1: adjacency  a[b][m][n] = 0.5*(w_norm[m][n] + (m==n))
// (rows of w+I sum to exactly 2 -> dinv = 1/sqrt(2) -> scale 0.5)
// ---------------------------------------------------------------------------
__global__ void adj_kernel(const float* __restrict__ locs, float* __restrict__ a) {
  int b = blockIdx.x;
  int m = threadIdx.x;  // 64 threads
  __shared__ float lx[64], ly[64];
  lx[m] = locs[(b * 64 + m) * 2 + 0];
  ly[m] = locs[(b * 64 + m) * 2 + 1];
  __syncthreads();
  float x = lx[m], y = ly[m];
  float sum = 0.f;
  for (int n = 0; n < 64; ++n) {
    float dx = x - lx[n], dy = y - ly[n];
    float d = sqrtf(dx * dx + dy * dy + 1e-12f);
    float w = (n == m) ? 0.f : 1.f / d;
    sum += w;
  }
  float inv = 0.5f / sum;
  for (int n = 0; n < 64; ++n) {
    float dx = x - lx[n], dy = y - ly[n];
    float d = sqrtf(dx * dx + dy * dy + 1e-12f);
    float w = (n == m) ? 0.5f : inv / d;
    a[(b * 64 + m) * 64 + n] = w;
  }
}

// ---------------------------------------------------------------------------
// Kernel 2: fused GCN front-end for one (b,t) within a batch chunk [b0, b0+CB):
//   xa[m][f] = sum_n a[b][m][n] * x[b][n][t][f]
//   G[lrow][d]      = relu(sum_f xa[m][f]*gcn_w[f][d] + gcn_b[d])   (chunk-local row)
//   tok[lrow][0..7] = x + pos_em
// NOTE: pos_em pointer is already offset to the chunk (b0) -> index with bl.
// ---------------------------------------------------------------------------
__global__ __launch_bounds__(256) void gcn_kernel(
    const float* __restrict__ x, const float* __restrict__ adj,
    const float* __restrict__ gcn_w, const float* __restrict__ gcn_b,
    const float* __restrict__ pos_em, float* __restrict__ G, float* __restrict__ tok,
    int b0) {
  int bl = blockIdx.x / T_;       // chunk-local batch
  int t = blockIdx.x % T_;
  int b = b0 + bl;                // global batch (for x, adj)
  int tid = threadIdx.x;
  __shared__ float sX[512];   // x[b,:,t,:]  [64][8]
  __shared__ float sXA[512];  // xa          [64][8]
  const float* adjb = adj + b * 4096;
  for (int i = tid; i < 512; i += 256) {
    int n = i >> 3, f = i & 7;
    sX[i] = x[((long)(b * 64 + n) * T_ + t) * F_ + f];
  }
  __syncthreads();
  for (int i = tid; i < 512; i += 256) {
    int m = i >> 3, f = i & 7;
    float s = 0.f;
    for (int n = 0; n < 64; ++n) s += adjb[(m << 6) + n] * sX[(n << 3) + f];
    sXA[i] = s;
  }
  // tok x-part (cols 0..7), + pos_em  (chunk-local batch index!)
  {
    long pbase = ((long)bl * T_ + t) * E_;
    for (int i = tid; i < 512; i += 256) {
      int m = i >> 3, f = i & 7;
      long lrow = (long)(bl * 64 + m) * T_ + t;
      tok[lrow * E_ + f] = sX[i] + pos_em[pbase + f];
    }
  }
  __syncthreads();
  for (int i = tid; i < 64 * 248; i += 256) {
    int m = i / 248, d = i % 248;
    float s = gcn_b[d];
    const float* xam = &sXA[m << 3];
#pragma unroll
    for (int f = 0; f < 8; ++f) s += xam[f] * gcn_w[f * 248 + d];
    long lrow = (long)(bl * 64 + m) * T_ + t;
    G[lrow * 248 + d] = fmaxf(s, 0.f);
  }
}

// ---------------------------------------------------------------------------
// Generic tiled f32 GEMM: C[:,c0:c0+N] = op(A[M,K] @ Bm[K,N])
//   Aadd/Eadd: embedding tensors (ld 256) indexed via row -> (row/NT)*T + row%T
//   (base pointers already offset to the chunk's first batch; rows chunk-local)
//   bias[N], relu, Cres residual (may alias C element-wise).
// Tiles: 128x128, K-step 16, 256 threads, 8x8 micro-tile. K/N guards (M %128 == 0).
// ---------------------------------------------------------------------------
__global__ __launch_bounds__(256) void gemm_kernel(
    const float* __restrict__ A, int lda,
    const float* __restrict__ Bm, int ldb,
    float* C, int ldc, int c0,
    const float* __restrict__ bias,
    const float* __restrict__ Aadd,
    const float* __restrict__ Eadd,
    const float* Cres,
    int M, int N, int K, int relu) {
  __shared__ float As[16][132];
  __shared__ float Bs[16][128];
  int tid = threadIdx.x;
  int m0 = blockIdx.x * 128, n0 = blockIdx.y * 128;
  int ty = tid >> 4, tx = tid & 15;
  float acc[8][8] = {};
  int nkt = (K + 15) >> 4;
  for (int kt = 0; kt < nkt; ++kt) {
    int k0 = kt << 4;
#pragma unroll
    for (int i = 0; i < 8; ++i) {
      int idx = i * 256 + tid;
      int mm = idx >> 4, kk = idx & 15;
      int k = k0 + kk;
      int row = m0 + mm;
      float v = 0.f;
      if (k < K) {
        v = A[(long)row * lda + k];
        if (Aadd) {
          int ar = (row / NT_) * T_ + (row % T_);
          v += Aadd[(long)ar * 256 + k];
        }
      }
      As[kk][mm] = v;
    }
#pragma unroll
    for (int i = 0; i < 8; ++i) {
      int idx = i * 256 + tid;
      int kk = idx >> 7, nn = idx & 127;
      int k = k0 + kk, n = n0 + nn;
      Bs[kk][nn] = (k < K && n < N) ? Bm[(long)k * ldb + n] : 0.f;
    }
    __syncthreads();
#pragma unroll
    for (int kk = 0; kk < 16; ++kk) {
      float af[8], bf[8];
#pragma unroll
      for (int i = 0; i < 8; ++i) af[i] = As[kk][ty * 8 + i];
#pragma unroll
      for (int j = 0; j < 8; ++j) bf[j] = Bs[kk][tx * 8 + j];
#pragma unroll
      for (int i = 0; i < 8; ++i)
#pragma unroll
        for (int j = 0; j < 8; ++j) acc[i][j] += af[i] * bf[j];
    }
    __syncthreads();
  }
#pragma unroll
  for (int i = 0; i < 8; ++i) {
    int row = m0 + ty * 8 + i;
    int ar = (row / NT_) * T_ + (row % T_);
#pragma unroll
    for (int j = 0; j < 8; ++j) {
      int col = n0 + tx * 8 + j;
      if (col < N) {
        float v = acc[i][j];
        if (bias) v += bias[col];
        if (relu) v = fmaxf(v, 0.f);
        if (Eadd) v += Eadd[(long)ar * 256 + c0 + col];
        if (Cres) v += Cres[(long)row * ldc + c0 + col];
        C[(long)row * ldc + c0 + col] = v;
      }
    }
  }
}

// ---------------------------------------------------------------------------
// Attention for one (bn_local, h). K/V staged in LDS, one thread per query row,
// online softmax. O may alias Q (each thread loads its q row to regs first).
// ---------------------------------------------------------------------------
__global__ __launch_bounds__(192) void attn_kernel(
    const float* Q, const float* __restrict__ Kb,
    const float* __restrict__ V, float* O) {
  int blk = blockIdx.x;
  int bn = blk >> 3, h = blk & 7;
  int tid = threadIdx.x;
  __shared__ float sK[T_][DH_];
  __shared__ float sV[T_][DH_];
  const long base = (long)bn * T_ * E_ + h * DH_;
  for (int i = tid; i < T_ * DH_; i += 192) {
    int r = i >> 5, d = i & 31;
    sK[r][d] = Kb[base + (long)r * E_ + d];
    sV[r][d] = V[base + (long)r * E_ + d];
  }
  __syncthreads();
  if (tid < T_) {
    float qr[DH_];
#pragma unroll
    for (int d = 0; d < DH_; ++d) qr[d] = Q[base + (long)tid * E_ + d];
    float mval = -1e30f, l = 0.f;
    float acc[DH_];
#pragma unroll
    for (int d = 0; d < DH_; ++d) acc[d] = 0.f;
    const float scale = 0.17677669529663687f;  // 1/sqrt(32)
    for (int j = 0; j < T_; ++j) {
      float s = 0.f;
#pragma unroll
      for (int d = 0; d < DH_; ++d) s += qr[d] * sK[j][d];
      s *= scale;
      float nm = fmaxf(mval, s);
      float f = __expf(mval - nm);
      float p = __expf(s - nm);
      l = l * f + p;
#pragma unroll
      for (int d = 0; d < DH_; ++d) acc[d] = acc[d] * f + p * sV[j][d];
      mval = nm;
    }
    float inv = 1.f / l;
#pragma unroll
    for (int d = 0; d < DH_; ++d) O[base + (long)tid * E_ + d] = acc[d] * inv;
  }
}

// ---------------------------------------------------------------------------
// In-place LayerNorm over rows of 256
// ---------------------------------------------------------------------------
__global__ __launch_bounds__(256) void ln_kernel(float* X, const float* __restrict__ g,
                                                 const float* __restrict__ bt) {
  long row = blockIdx.x;
  int tid = threadIdx.x;
  float v = X[row * 256 + tid];
  float s = v, s2 = v * v;
#pragma unroll
  for (int off = 32; off > 0; off >>= 1) {
    s += __shfl_down(s, off, 64);
    s2 += __shfl_down(s2, off, 64);
  }
  __shared__ float r1[4], r2[4];
  int w = tid >> 6;
  if ((tid & 63) == 0) { r1[w] = s; r2[w] = s2; }
  __syncthreads();
  float S = r1[0] + r1[1] + r1[2] + r1[3];
  float S2 = r2[0] + r2[1] + r2[2] + r2[3];
  float mean = S * 0.00390625f;
  float var = S2 * 0.00390625f - mean * mean;
  float rs = rsqrtf(var + 1e-5f);
  X[row * 256 + tid] = (v - mean) * rs * g[tid] + bt[tid];
}

// ---------------------------------------------------------------------------
extern "C" void kernel_launch(void* const* d_in, const int* in_sizes, int n_in,
                              void* d_out, int out_size, void* d_ws, size_t ws_size,
                              hipStream_t stream) {
  const float* x      = (const float*)d_in[0];
  const float* locs   = (const float*)d_in[1];
  const float* pos_em = (const float*)d_in[2];
  const float* per_em = (const float*)d_in[3];
  const float* gcn_w  = (const float*)d_in[4];
  const float* gcn_b  = (const float*)d_in[5];
  const float* fc1_w  = (const float*)d_in[6];
  const float* fc1_b  = (const float*)d_in[7];
  const float* wq = (const float*)d_in[8];
  const float* bq = (const float*)d_in[9];
  const float* wk = (const float*)d_in[10];
  const float* bk = (const float*)d_in[11];
  const float* wv = (const float*)d_in[12];
  const float* bv = (const float*)d_in[13];
  const float* wo = (const float*)d_in[14];
  const float* bo = (const float*)d_in[15];
  const float* ln1_g = (const float*)d_in[16];
  const float* ln1_b = (const float*)d_in[17];
  const float* ln2_g = (const float*)d_in[18];
  const float* ln2_b = (const float*)d_in[19];
  const float* ff1_w = (const float*)d_in[20];
  const float* ff1_b = (const float*)d_in[21];
  const float* ff2_w = (const float*)d_in[22];
  const float* ff2_b = (const float*)d_in[23];
  float* out = (float*)d_out;

  // ---- adaptive batch chunking so workspace always fits -------------------
  const size_t ADJ_BYTES = 1u << 20;  // 256 KB used, 1 MB reserved
  int CB = 16;
  while (CB > 1) {
    size_t slot = (size_t)CB * NT_ * E_ * sizeof(float);
    if (ADJ_BYTES + 4 * slot <= ws_size) break;
    CB >>= 1;
  }
  const size_t SLOT = (size_t)CB * NT_ * E_ * sizeof(float);

  char* ws = (char*)d_ws;
  float* adj = (float*)ws;
  float* tok = (float*)(ws + ADJ_BYTES);
  float* qb  = (float*)(ws + ADJ_BYTES + SLOT);      // G, then Q, then O
  float* kb  = (float*)(ws + ADJ_BYTES + 2 * SLOT);  // K, then FF intermediate (w/ vb)
  float* vb  = (float*)(ws + ADJ_BYTES + 3 * SLOT);  // V

  adj_kernel<<<B_, 64, 0, stream>>>(locs, adj);

  for (int b0 = 0; b0 < B_; b0 += CB) {
    const int rows = CB * NT_;                     // multiple of 128 (10752 = 84*128)
    const float* pos_c = pos_em + (long)b0 * T_ * E_;
    const float* per_c = per_em + (long)b0 * T_ * E_;
    float* out_c = out + (long)b0 * NT_ * E_;
    float* G = qb;

    gcn_kernel<<<CB * T_, 256, 0, stream>>>(x, adj, gcn_w, gcn_b, pos_c, G, tok, b0);

    // fc1: tok[:,8:256] = G @ fc1_w + fc1_b + pos_em[:,8:256]
    {
      dim3 g(rows / 128, 2);
      gemm_kernel<<<g, 256, 0, stream>>>(G, 248, fc1_w, 248, tok, 256, 8,
                                         fc1_b, nullptr, pos_c, nullptr,
                                         rows, 248, 248, 0);
    }
    // Q, K (periodic embedding on inputs), V
    {
      dim3 g(rows / 128, 2);
      gemm_kernel<<<g, 256, 0, stream>>>(tok, 256, wq, 256, qb, 256, 0,
                                         bq, per_c, nullptr, nullptr,
                                         rows, 256, 256, 0);
      gemm_kernel<<<g, 256, 0, stream>>>(tok, 256, wk, 256, kb, 256, 0,
                                         bk, per_c, nullptr, nullptr,
                                         rows, 256, 256, 0);
      gemm_kernel<<<g, 256, 0, stream>>>(tok, 256, wv, 256, vb, 256, 0,
                                         bv, nullptr, nullptr, nullptr,
                                         rows, 256, 256, 0);
    }
    // attention (O in-place over Q)
    attn_kernel<<<CB * N_ * H_, 192, 0, stream>>>(qb, kb, vb, qb);
    // out_c = tok + O @ wo + bo ; then LN1 in place -> h1
    {
      dim3 g(rows / 128, 2);
      gemm_kernel<<<g, 256, 0, stream>>>(qb, 256, wo, 256, out_c, 256, 0,
                                         bo, nullptr, nullptr, tok,
                                         rows, 256, 256, 0);
    }
    ln_kernel<<<rows, 256, 0, stream>>>(out_c, ln1_g, ln1_b);
    // FF in 2 row sub-chunks; intermediate reuses K+V slots (2*SLOT bytes)
    {
      const int CHR = rows / 2;  // multiple of 128
      float* ffi = kb;
      for (int c = 0; c < 2; ++c) {
        float* h1c = out_c + (long)c * CHR * E_;
        dim3 g1(CHR / 128, 8);
        gemm_kernel<<<g1, 256, 0, stream>>>(h1c, 256, ff1_w, 1024, ffi, 1024, 0,
                                            ff1_b, nullptr, nullptr, nullptr,
                                            CHR, 1024, 256, 1);
        dim3 g2(CHR / 128, 2);
        gemm_kernel<<<g2, 256, 0, stream>>>(ffi, 1024, ff2_w, 256, h1c, 256, 0,
                                            ff2_b, nullptr, nullptr, h1c,
                                            CHR, 256, 1024, 0);
      }
    }
    ln_kernel<<<rows, 256, 0, stream>>>(out_c, ln2_g, ln2_b);
  }
}

// Round 4
// 3069.271 us; speedup vs baseline: 3.2309x; 3.2309x over previous
//
#include <hip/hip_runtime.h>
#include <hip/hip_bf16.h>

// Problem dims
constexpr int B_  = 16;
constexpr int N_  = 64;     // stations
constexpr int T_  = 168;    // seq
constexpr int F_  = 8;      // raw features
constexpr int D_  = 248;    // gcn dim
constexpr int E_  = 256;    // dmodel
constexpr int H_  = 8;      // heads
constexpr int DH_ = 32;     // head dim
constexpr int FF_ = 1024;   // ff dim
constexpr int BN_ = B_ * N_;           // 1024
constexpr int NT_ = N_ * T_;           // 10752 (rows per batch)

typedef __bf16 bf16x8 __attribute__((ext_vector_type(8)));
typedef float  f32x4  __attribute__((ext_vector_type(4)));

__device__ __forceinline__ unsigned short f2b(float f) {
  union { float f; unsigned int u; } v; v.f = f;
  unsigned int r = (v.u + 0x7FFFu + ((v.u >> 16) & 1u)) >> 16;
  return (unsigned short)r;
}
__device__ __forceinline__ float b2f(unsigned short h) {
  union { unsigned int u; float f; } v; v.u = ((unsigned int)h) << 16;
  return v.f;
}
__device__ __forceinline__ void gload16(const void* g, void* l) {
  __builtin_amdgcn_global_load_lds(
      (const __attribute__((address_space(1))) unsigned int*)g,
      (__attribute__((address_space(3))) unsigned int*)l, 16, 0, 0);
}

// ---------------------------------------------------------------------------
// adjacency  a[b][m][n] = 0.5*(w_norm[m][n] + (m==n))
// ---------------------------------------------------------------------------
__global__ void adj_kernel(const float* __restrict__ locs, float* __restrict__ a) {
  int b = blockIdx.x;
  int m = threadIdx.x;  // 64 threads
  __shared__ float lx[64], ly[64];
  lx[m] = locs[(b * 64 + m) * 2 + 0];
  ly[m] = locs[(b * 64 + m) * 2 + 1];
  __syncthreads();
  float x = lx[m], y = ly[m];
  float sum = 0.f;
  for (int n = 0; n < 64; ++n) {
    float dx = x - lx[n], dy = y - ly[n];
    float d = sqrtf(dx * dx + dy * dy + 1e-12f);
    sum += (n == m) ? 0.f : 1.f / d;
  }
  float inv = 0.5f / sum;
  for (int n = 0; n < 64; ++n) {
    float dx = x - lx[n], dy = y - ly[n];
    float d = sqrtf(dx * dx + dy * dy + 1e-12f);
    float w = (n == m) ? 0.5f : inv / d;
    a[(b * 64 + m) * 64 + n] = w;
  }
}

// ---------------------------------------------------------------------------
// weight convert: in f32 [K][N] (ld N) -> outT bf16 [Np][Kp] (ld Kp), zero pad
// ---------------------------------------------------------------------------
__global__ void convw_kernel(const float* __restrict__ in, unsigned short* __restrict__ outT,
                             int K, int N, int Kp, int Np) {
  int idx = blockIdx.x * 256 + threadIdx.x;
  if (idx >= Np * Kp) return;
  int n = idx / Kp, k = idx % Kp;
  float v = (k < K && n < N) ? in[(long)k * N + n] : 0.f;
  outT[idx] = f2b(v);
}

// ---------------------------------------------------------------------------
// GCN front-end for one (b,t) in chunk [b0, b0+CB):
//   G[lrow][0..255]  = relu(xa@gcn_w + gcn_b) bf16 (cols 248..255 = 0)
//   tokb[lrow][0..7] = bf16(x + pos_em);  qkb[lrow][0..7] = bf16(x+pos+per)
// pos/per pointers already chunk-offset -> index with bl.
// ---------------------------------------------------------------------------
__global__ __launch_bounds__(256) void gcn_kernel(
    const float* __restrict__ x, const float* __restrict__ adj,
    const float* __restrict__ gcn_w, const float* __restrict__ gcn_b,
    const float* __restrict__ pos_em, const float* __restrict__ per_em,
    unsigned short* __restrict__ G, unsigned short* __restrict__ tokb,
    unsigned short* __restrict__ qkb, int b0) {
  int bl = blockIdx.x / T_;
  int t = blockIdx.x % T_;
  int b = b0 + bl;
  int tid = threadIdx.x;
  __shared__ float sX[512];   // x[b,:,t,:]  [64][8]
  __shared__ float sXA[512];  // xa          [64][8]
  const float* adjb = adj + b * 4096;
  for (int i = tid; i < 512; i += 256) {
    int n = i >> 3, f = i & 7;
    sX[i] = x[((long)(b * 64 + n) * T_ + t) * F_ + f];
  }
  __syncthreads();
  for (int i = tid; i < 512; i += 256) {
    int m = i >> 3, f = i & 7;
    float s = 0.f;
    for (int n = 0; n < 64; ++n) s += adjb[(m << 6) + n] * sX[(n << 3) + f];
    sXA[i] = s;
  }
  {
    long pbase = ((long)bl * T_ + t) * E_;
    for (int i = tid; i < 512; i += 256) {
      int m = i >> 3, f = i & 7;
      long lrow = (long)(bl * 64 + m) * T_ + t;
      float base = sX[i] + pos_em[pbase + f];
      tokb[lrow * E_ + f] = f2b(base);
      qkb[lrow * E_ + f]  = f2b(base + per_em[pbase + f]);
    }
  }
  __syncthreads();
  for (int i = tid; i < 64 * 256; i += 256) {
    int m = i >> 8, d = i & 255;
    float v = 0.f;
    if (d < 248) {
      float s = gcn_b[d];
      const float* xam = &sXA[m << 3];
#pragma unroll
      for (int f = 0; f < 8; ++f) s += xam[f] * gcn_w[f * 248 + d];
      v = fmaxf(s, 0.f);
    }
    long lrow = (long)(bl * 64 + m) * T_ + t;
    G[lrow * 256 + d] = f2b(v);
  }
}

// ---------------------------------------------------------------------------
// bf16 MFMA GEMM (m97 structure): 128x128 tile, BK=64, 4 waves (2x2),
// global_load_lds(16B) staging, ds_read_b128 fragments, f32 acc.
//   A [M][lda] bf16, Bt [Npad][K] bf16 (pre-transposed weights, K%64==0,
//   Npad%128==0), M%128==0. grid=(M/128, Npad/128).
// Epilogue per cell (gcol<Nact): base = acc+bias, relu, +resb(bf16,ld256),
//   +resf(f32,ldc; may alias Cf), e1=emb1[ar], e2=emb2[ar]:
//   Cf = base+e1 (f32) ; Cb1 = bf16(base+e1) ; Cb2 = bf16(base+e1+e2)
// ar = (row/NT)*T + row%T (embedding ld 256, col offset c0).
// ---------------------------------------------------------------------------
__global__ __launch_bounds__(256) void mfma_gemm(
    const unsigned short* __restrict__ A, int lda,
    const unsigned short* __restrict__ Bt, int K, int Nact,
    const float* __restrict__ bias,
    float* Cf, unsigned short* Cb1, unsigned short* Cb2,
    const float* __restrict__ emb1, const float* __restrict__ emb2,
    const unsigned short* __restrict__ resb, const float* resf,
    int c0, int ldc, int relu) {
  __shared__ unsigned short As[128 * 64];
  __shared__ unsigned short Bs[128 * 64];
  int tid = threadIdx.x;
  int lane = tid & 63, wid = tid >> 6;
  int wm = wid >> 1, wn = wid & 1;
  int m0 = blockIdx.x * 128, n0 = blockIdx.y * 128;
  f32x4 acc[4][4];
#pragma unroll
  for (int i = 0; i < 4; ++i)
#pragma unroll
    for (int j = 0; j < 4; ++j) acc[i][j] = (f32x4){0.f, 0.f, 0.f, 0.f};

  const unsigned short* Ab = A + (long)m0 * lda;
  const unsigned short* Bb = Bt + (long)n0 * K;
  int srow = tid >> 3;            // 0..31 (wave w covers rows w*8..w*8+7)
  int scol = (tid & 7) << 3;      // k-elem offset
  int ldsrow0 = (wid << 3);       // wave-uniform row base within 32-row group

  int nk = K >> 6;
  for (int kt = 0; kt < nk; ++kt) {
    int k0 = kt << 6;
#pragma unroll
    for (int i = 0; i < 4; ++i) {
      gload16(Ab + (long)((i << 5) + srow) * lda + k0 + scol,
              &As[(((i << 5) + ldsrow0) << 6)]);
      gload16(Bb + (long)((i << 5) + srow) * K + k0 + scol,
              &Bs[(((i << 5) + ldsrow0) << 6)]);
    }
    __syncthreads();
    int arow = ((wm << 6) + (lane & 15)) << 6;   // + mf*16*64
    int brow = ((wn << 6) + (lane & 15)) << 6;
    int koff = ((lane >> 4) << 3);
#pragma unroll
    for (int ks = 0; ks < 2; ++ks) {
      bf16x8 af[4], bf[4];
#pragma unroll
      for (int mf = 0; mf < 4; ++mf)
        af[mf] = *reinterpret_cast<const bf16x8*>(&As[arow + (mf << 10) + (ks << 5) + koff]);
#pragma unroll
      for (int nf = 0; nf < 4; ++nf)
        bf[nf] = *reinterpret_cast<const bf16x8*>(&Bs[brow + (nf << 10) + (ks << 5) + koff]);
#pragma unroll
      for (int mf = 0; mf < 4; ++mf)
#pragma unroll
        for (int nf = 0; nf < 4; ++nf)
          acc[mf][nf] = __builtin_amdgcn_mfma_f32_16x16x32_bf16(af[mf], bf[nf], acc[mf][nf], 0, 0, 0);
    }
    __syncthreads();
  }

  // epilogue
  int cl = lane & 15;
  int rg = (lane >> 4) << 2;
#pragma unroll
  for (int mf = 0; mf < 4; ++mf) {
#pragma unroll
    for (int r = 0; r < 4; ++r) {
      int rr = m0 + (wm << 6) + (mf << 4) + rg + r;
      int ar = (rr / NT_) * T_ + (rr % T_);
      long rbase  = (long)rr * ldc + c0;
      long rbase2 = (long)rr * 256 + c0;
      long abase  = (long)ar * 256 + c0;
#pragma unroll
      for (int nf = 0; nf < 4; ++nf) {
        int gcol = n0 + (wn << 6) + (nf << 4) + cl;
        if (gcol < Nact) {
          float v = acc[mf][nf][r];
          if (bias) v += bias[gcol];
          if (relu) v = fmaxf(v, 0.f);
          if (resb) v += b2f(resb[rbase2 + gcol]);
          if (resf) v += resf[rbase + gcol];
          float e1 = emb1 ? emb1[abase + gcol] : 0.f;
          if (Cf)  Cf[rbase + gcol] = v + e1;
          if (Cb1) Cb1[rbase + gcol] = f2b(v + e1);
          if (Cb2) Cb2[rbase + gcol] = f2b(v + e1 + emb2[abase + gcol]);
        }
      }
    }
  }
}

// ---------------------------------------------------------------------------
// Attention for one (bn_local, h); bf16 in/out, f32 compute. O may alias Q.
// ---------------------------------------------------------------------------
__global__ __launch_bounds__(192) void attn_kernel(
    const unsigned short* Q, const unsigned short* __restrict__ Kb,
    const unsigned short* __restrict__ V, unsigned short* O) {
  int blk = blockIdx.x;
  int bn = blk >> 3, h = blk & 7;
  int tid = threadIdx.x;
  __shared__ float sK[T_][DH_];
  __shared__ float sV[T_][DH_];
  const long base = (long)bn * T_ * E_ + h * DH_;
  // vectorized staging: 168*32/8 = 672 uint4 loads per matrix
  for (int i = tid; i < T_ * 4; i += 192) {
    int r = i >> 2, seg = (i & 3) << 3;
    const ushort* pk = (const ushort*)(Kb + base + (long)r * E_ + seg);
    const ushort* pv = (const ushort*)(V + base + (long)r * E_ + seg);
    uint4 kv = *reinterpret_cast<const uint4*>(pk);
    uint4 vv = *reinterpret_cast<const uint4*>(pv);
    const unsigned int* ku = (const unsigned int*)&kv;
    const unsigned int* vu = (const unsigned int*)&vv;
#pragma unroll
    for (int j = 0; j < 4; ++j) {
      sK[r][seg + 2 * j]     = b2f((unsigned short)(ku[j] & 0xFFFF));
      sK[r][seg + 2 * j + 1] = b2f((unsigned short)(ku[j] >> 16));
      sV[r][seg + 2 * j]     = b2f((unsigned short)(vu[j] & 0xFFFF));
      sV[r][seg + 2 * j + 1] = b2f((unsigned short)(vu[j] >> 16));
    }
  }
  __syncthreads();
  if (tid < T_) {
    float qr[DH_];
#pragma unroll
    for (int d = 0; d < DH_; ++d) qr[d] = b2f(Q[base + (long)tid * E_ + d]);
    float mval = -1e30f, l = 0.f;
    float acc[DH_];
#pragma unroll
    for (int d = 0; d < DH_; ++d) acc[d] = 0.f;
    const float scale = 0.17677669529663687f;  // 1/sqrt(32)
    for (int j = 0; j < T_; ++j) {
      float s = 0.f;
#pragma unroll
      for (int d = 0; d < DH_; ++d) s += qr[d] * sK[j][d];
      s *= scale;
      float nm = fmaxf(mval, s);
      float f = __expf(mval - nm);
      float p = __expf(s - nm);
      l = l * f + p;
#pragma unroll
      for (int d = 0; d < DH_; ++d) acc[d] = acc[d] * f + p * sV[j][d];
      mval = nm;
    }
    float inv = 1.f / l;
#pragma unroll
    for (int d = 0; d < DH_; ++d) O[base + (long)tid * E_ + d] = f2b(acc[d] * inv);
  }
}

// ---------------------------------------------------------------------------
// In-place LayerNorm over rows of 256 (f32), optional bf16 copy out.
// ---------------------------------------------------------------------------
__global__ __launch_bounds__(256) void ln_kernel(float* X, const float* __restrict__ g,
                                                 const float* __restrict__ bt,
                                                 unsigned short* bout) {
  long row = blockIdx.x;
  int tid = threadIdx.x;
  float v = X[row * 256 + tid];
  float s = v, s2 = v * v;
#pragma unroll
  for (int off = 32; off > 0; off >>= 1) {
    s += __shfl_down(s, off, 64);
    s2 += __shfl_down(s2, off, 64);
  }
  __shared__ float r1[4], r2[4];
  int w = tid >> 6;
  if ((tid & 63) == 0) { r1[w] = s; r2[w] = s2; }
  __syncthreads();
  float S = r1[0] + r1[1] + r1[2] + r1[3];
  float S2 = r2[0] + r2[1] + r2[2] + r2[3];
  float mean = S * 0.00390625f;
  float var = S2 * 0.00390625f - mean * mean;
  float rs = rsqrtf(var + 1e-5f);
  float o = (v - mean) * rs * g[tid] + bt[tid];
  X[row * 256 + tid] = o;
  if (bout) bout[row * 256 + tid] = f2b(o);
}

// ---------------------------------------------------------------------------
extern "C" void kernel_launch(void* const* d_in, const int* in_sizes, int n_in,
                              void* d_out, int out_size, void* d_ws, size_t ws_size,
                              hipStream_t stream) {
  const float* x      = (const float*)d_in[0];
  const float* locs   = (const float*)d_in[1];
  const float* pos_em = (const float*)d_in[2];
  const float* per_em = (const float*)d_in[3];
  const float* gcn_w  = (const float*)d_in[4];
  const float* gcn_b  = (const float*)d_in[5];
  const float* fc1_w  = (const float*)d_in[6];
  const float* fc1_b  = (const float*)d_in[7];
  const float* wq = (const float*)d_in[8];
  const float* bq = (const float*)d_in[9];
  const float* wk = (const float*)d_in[10];
  const float* bk = (const float*)d_in[11];
  const float* wv = (const float*)d_in[12];
  const float* bv = (const float*)d_in[13];
  const float* wo = (const float*)d_in[14];
  const float* bo = (const float*)d_in[15];
  const float* ln1_g = (const float*)d_in[16];
  const float* ln1_b = (const float*)d_in[17];
  const float* ln2_g = (const float*)d_in[18];
  const float* ln2_b = (const float*)d_in[19];
  const float* ff1_w = (const float*)d_in[20];
  const float* ff1_b = (const float*)d_in[21];
  const float* ff2_w = (const float*)d_in[22];
  const float* ff2_b = (const float*)d_in[23];
  float* out = (float*)d_out;

  // ---- workspace layout ---------------------------------------------------
  const size_t ADJ_BYTES = 1u << 20;            // adjacency (f32, 256KB used)
  const size_t WB_BYTES  = 2u << 20;            // bf16 transposed weights
  const size_t SLOT1 = (size_t)NT_ * E_ * 2;    // 5.5 MB per batch per slot
  int CB = 16;
  while (CB > 1) {
    if (ADJ_BYTES + WB_BYTES + 5 * (size_t)CB * SLOT1 <= ws_size) break;
    CB >>= 1;
  }
  char* ws = (char*)d_ws;
  float* adj = (float*)ws;
  unsigned short* wslab = (unsigned short*)(ws + ADJ_BYTES);
  unsigned short* fc1T = wslab;                 // [256][256]
  unsigned short* wqT  = wslab + 65536;
  unsigned short* wkT  = wslab + 2 * 65536;
  unsigned short* wvT  = wslab + 3 * 65536;
  unsigned short* woT  = wslab + 4 * 65536;
  unsigned short* ff1T = wslab + 5 * 65536;     // [1024][256]
  unsigned short* ff2T = wslab + 5 * 65536 + 262144;  // [256][1024]

  const size_t SLOT = (size_t)CB * SLOT1;
  unsigned short* tokb = (unsigned short*)(ws + ADJ_BYTES + WB_BYTES);
  unsigned short* qkb  = tokb + SLOT / 2;       // slot offsets in ushorts
  unsigned short* qb   = tokb + 2 * (SLOT / 2);
  unsigned short* kb   = tokb + 3 * (SLOT / 2);
  unsigned short* vb   = tokb + 4 * (SLOT / 2);
  unsigned short* G    = qb;                    // GCN hidden until fc1 consumes it
  unsigned short* ffi  = qkb;                   // FF intermediate: slots 1..4 (qkb,qb,kb,vb)
  unsigned short* h1b  = tokb;                  // bf16 copy of LN1 out

  adj_kernel<<<B_, 64, 0, stream>>>(locs, adj);
  convw_kernel<<<(65536 + 255) / 256, 256, 0, stream>>>(fc1_w, fc1T, 248, 248, 256, 256);
  convw_kernel<<<(65536 + 255) / 256, 256, 0, stream>>>(wq, wqT, 256, 256, 256, 256);
  convw_kernel<<<(65536 + 255) / 256, 256, 0, stream>>>(wk, wkT, 256, 256, 256, 256);
  convw_kernel<<<(65536 + 255) / 256, 256, 0, stream>>>(wv, wvT, 256, 256, 256, 256);
  convw_kernel<<<(65536 + 255) / 256, 256, 0, stream>>>(wo, woT, 256, 256, 256, 256);
  convw_kernel<<<(262144 + 255) / 256, 256, 0, stream>>>(ff1_w, ff1T, 256, 1024, 256, 1024);
  convw_kernel<<<(262144 + 255) / 256, 256, 0, stream>>>(ff2_w, ff2T, 1024, 256, 1024, 256);

  for (int b0 = 0; b0 < B_; b0 += CB) {
    const int rows = CB * NT_;      // multiple of 128
    const int MB = rows / 128;
    const float* pos_c = pos_em + (long)b0 * T_ * E_;
    const float* per_c = per_em + (long)b0 * T_ * E_;
    float* out_c = out + (long)b0 * NT_ * E_;

    gcn_kernel<<<CB * T_, 256, 0, stream>>>(x, adj, gcn_w, gcn_b, pos_c, per_c,
                                            G, tokb, qkb, b0);
    // fc1 -> tokb[:,8:256] (+pos) and qkb[:,8:256] (+pos+per)
    {
      dim3 g(MB, 2);
      mfma_gemm<<<g, 256, 0, stream>>>(G, 256, fc1T, 256, 248, fc1_b,
                                       nullptr, tokb, qkb, pos_c, per_c,
                                       nullptr, nullptr, 8, 256, 0);
    }
    // Q, K, V
    {
      dim3 g(MB, 2);
      mfma_gemm<<<g, 256, 0, stream>>>(qkb, 256, wqT, 256, 256, bq,
                                       nullptr, qb, nullptr, nullptr, nullptr,
                                       nullptr, nullptr, 0, 256, 0);
      mfma_gemm<<<g, 256, 0, stream>>>(qkb, 256, wkT, 256, 256, bk,
                                       nullptr, kb, nullptr, nullptr, nullptr,
                                       nullptr, nullptr, 0, 256, 0);
      mfma_gemm<<<g, 256, 0, stream>>>(tokb, 256, wvT, 256, 256, bv,
                                       nullptr, vb, nullptr, nullptr, nullptr,
                                       nullptr, nullptr, 0, 256, 0);
    }
    // attention (O in-place over Q)
    attn_kernel<<<CB * N_ * H_, 192, 0, stream>>>(qb, kb, vb, qb);
    // out_c = tokb + O @ wo + bo ; LN1 in place (+ bf16 copy h1b)
    {
      dim3 g(MB, 2);
      mfma_gemm<<<g, 256, 0, stream>>>(qb, 256, woT, 256, 256, bo,
                                       out_c, nullptr, nullptr, nullptr, nullptr,
                                       tokb, nullptr, 0, 256, 0);
    }
    ln_kernel<<<rows, 256, 0, stream>>>(out_c, ln1_g, ln1_b, h1b);
    // FF1: ffi = relu(h1b @ ff1_w + b)   [rows x 1024 bf16]
    {
      dim3 g(MB, 8);
      mfma_gemm<<<g, 256, 0, stream>>>(h1b, 256, ff1T, 256, 1024, ff1_b,
                                       nullptr, ffi, nullptr, nullptr, nullptr,
                                       nullptr, nullptr, 0, 1024, 1);
    }
    // FF2: out_c = h1 + ffi @ ff2_w + b  (resf aliases Cf, per-cell safe)
    {
      dim3 g(MB, 2);
      mfma_gemm<<<g, 256, 0, stream>>>(ffi, 1024, ff2T, 1024, 256, ff2_b,
                                       out_c, nullptr, nullptr, nullptr, nullptr,
                                       nullptr, out_c, 0, 256, 0);
    }
    ln_kernel<<<rows, 256, 0, stream>>>(out_c, ln2_g, ln2_b, nullptr);
  }
}

// Round 5
// 2466.729 us; speedup vs baseline: 4.0200x; 1.2443x over previous
//
#include <hip/hip_runtime.h>
#include <hip/hip_bf16.h>

// Problem dims
constexpr int B_  = 16;
constexpr int N_  = 64;     // stations
constexpr int T_  = 168;    // seq
constexpr int F_  = 8;      // raw features
constexpr int D_  = 248;    // gcn dim
constexpr int E_  = 256;    // dmodel
constexpr int H_  = 8;      // heads
constexpr int DH_ = 32;     // head dim
constexpr int FF_ = 1024;   // ff dim
constexpr int BN_ = B_ * N_;           // 1024
constexpr int NT_ = N_ * T_;           // 10752 (rows per batch)

typedef __bf16 bf16x8 __attribute__((ext_vector_type(8)));
typedef float  f32x4  __attribute__((ext_vector_type(4)));

__device__ __forceinline__ unsigned short f2b(float f) {
  union { float f; unsigned int u; } v; v.f = f;
  unsigned int r = (v.u + 0x7FFFu + ((v.u >> 16) & 1u)) >> 16;
  return (unsigned short)r;
}
__device__ __forceinline__ float b2f(unsigned short h) {
  union { unsigned int u; float f; } v; v.u = ((unsigned int)h) << 16;
  return v.f;
}
__device__ __forceinline__ void gload16(const void* g, void* l) {
  __builtin_amdgcn_global_load_lds(
      (const __attribute__((address_space(1))) unsigned int*)g,
      (__attribute__((address_space(3))) unsigned int*)l, 16, 0, 0);
}

// ---------------------------------------------------------------------------
// adjacency  a[b][m][n] = 0.5*(w_norm[m][n] + (m==n))
// ---------------------------------------------------------------------------
__global__ void adj_kernel(const float* __restrict__ locs, float* __restrict__ a) {
  int b = blockIdx.x;
  int m = threadIdx.x;  // 64 threads
  __shared__ float lx[64], ly[64];
  lx[m] = locs[(b * 64 + m) * 2 + 0];
  ly[m] = locs[(b * 64 + m) * 2 + 1];
  __syncthreads();
  float x = lx[m], y = ly[m];
  float sum = 0.f;
  for (int n = 0; n < 64; ++n) {
    float dx = x - lx[n], dy = y - ly[n];
    float d = sqrtf(dx * dx + dy * dy + 1e-12f);
    sum += (n == m) ? 0.f : 1.f / d;
  }
  float inv = 0.5f / sum;
  for (int n = 0; n < 64; ++n) {
    float dx = x - lx[n], dy = y - ly[n];
    float d = sqrtf(dx * dx + dy * dy + 1e-12f);
    float w = (n == m) ? 0.5f : inv / d;
    a[(b * 64 + m) * 64 + n] = w;
  }
}

// ---------------------------------------------------------------------------
// weight convert: in f32 [K][N] (ld N) -> outT bf16 [Np][Kp] (ld Kp), zero pad
// ---------------------------------------------------------------------------
__global__ void convw_kernel(const float* __restrict__ in, unsigned short* __restrict__ outT,
                             int K, int N, int Kp, int Np) {
  int idx = blockIdx.x * 256 + threadIdx.x;
  if (idx >= Np * Kp) return;
  int n = idx / Kp, k = idx % Kp;
  float v = (k < K && n < N) ? in[(long)k * N + n] : 0.f;
  outT[idx] = f2b(v);
}

// ---------------------------------------------------------------------------
// GCN front-end for one (b,t) in chunk [b0, b0+CB):
//   G[lrow][0..255]  = relu(xa@gcn_w + gcn_b) bf16 (cols 248..255 = 0)
//   tokb[lrow][0..7] = bf16(x + pos_em);  qkb[lrow][0..7] = bf16(x+pos+per)
// pos/per pointers already chunk-offset -> index with bl.
// ---------------------------------------------------------------------------
__global__ __launch_bounds__(256) void gcn_kernel(
    const float* __restrict__ x, const float* __restrict__ adj,
    const float* __restrict__ gcn_w, const float* __restrict__ gcn_b,
    const float* __restrict__ pos_em, const float* __restrict__ per_em,
    unsigned short* __restrict__ G, unsigned short* __restrict__ tokb,
    unsigned short* __restrict__ qkb, int b0) {
  int bl = blockIdx.x / T_;
  int t = blockIdx.x % T_;
  int b = b0 + bl;
  int tid = threadIdx.x;
  __shared__ float sX[512];   // x[b,:,t,:]  [64][8]
  __shared__ float sXA[512];  // xa          [64][8]
  const float* adjb = adj + b * 4096;
  for (int i = tid; i < 512; i += 256) {
    int n = i >> 3, f = i & 7;
    sX[i] = x[((long)(b * 64 + n) * T_ + t) * F_ + f];
  }
  __syncthreads();
  for (int i = tid; i < 512; i += 256) {
    int m = i >> 3, f = i & 7;
    float s = 0.f;
    for (int n = 0; n < 64; ++n) s += adjb[(m << 6) + n] * sX[(n << 3) + f];
    sXA[i] = s;
  }
  {
    long pbase = ((long)bl * T_ + t) * E_;
    for (int i = tid; i < 512; i += 256) {
      int m = i >> 3, f = i & 7;
      long lrow = (long)(bl * 64 + m) * T_ + t;
      float base = sX[i] + pos_em[pbase + f];
      tokb[lrow * E_ + f] = f2b(base);
      qkb[lrow * E_ + f]  = f2b(base + per_em[pbase + f]);
    }
  }
  __syncthreads();
  for (int i = tid; i < 64 * 256; i += 256) {
    int m = i >> 8, d = i & 255;
    float v = 0.f;
    if (d < 248) {
      float s = gcn_b[d];
      const float* xam = &sXA[m << 3];
#pragma unroll
      for (int f = 0; f < 8; ++f) s += xam[f] * gcn_w[f * 248 + d];
      v = fmaxf(s, 0.f);
    }
    long lrow = (long)(bl * 64 + m) * T_ + t;
    G[lrow * 256 + d] = f2b(v);
  }
}

// ---------------------------------------------------------------------------
// bf16 MFMA GEMM (m97 structure): 128x128 tile, BK=64, 4 waves (2x2),
// global_load_lds(16B) staging, ds_read_b128 fragments, f32 acc.
// ---------------------------------------------------------------------------
__global__ __launch_bounds__(256) void mfma_gemm(
    const unsigned short* __restrict__ A, int lda,
    const unsigned short* __restrict__ Bt, int K, int Nact,
    const float* __restrict__ bias,
    float* Cf, unsigned short* Cb1, unsigned short* Cb2,
    const float* __restrict__ emb1, const float* __restrict__ emb2,
    const unsigned short* __restrict__ resb, const float* resf,
    int c0, int ldc, int relu) {
  __shared__ unsigned short As[128 * 64];
  __shared__ unsigned short Bs[128 * 64];
  int tid = threadIdx.x;
  int lane = tid & 63, wid = tid >> 6;
  int wm = wid >> 1, wn = wid & 1;
  int m0 = blockIdx.x * 128, n0 = blockIdx.y * 128;
  f32x4 acc[4][4];
#pragma unroll
  for (int i = 0; i < 4; ++i)
#pragma unroll
    for (int j = 0; j < 4; ++j) acc[i][j] = (f32x4){0.f, 0.f, 0.f, 0.f};

  const unsigned short* Ab = A + (long)m0 * lda;
  const unsigned short* Bb = Bt + (long)n0 * K;
  int srow = tid >> 3;            // 0..31 (wave w covers rows w*8..w*8+7)
  int scol = (tid & 7) << 3;      // k-elem offset
  int ldsrow0 = (wid << 3);       // wave-uniform row base within 32-row group

  int nk = K >> 6;
  for (int kt = 0; kt < nk; ++kt) {
    int k0 = kt << 6;
#pragma unroll
    for (int i = 0; i < 4; ++i) {
      gload16(Ab + (long)((i << 5) + srow) * lda + k0 + scol,
              &As[(((i << 5) + ldsrow0) << 6)]);
      gload16(Bb + (long)((i << 5) + srow) * K + k0 + scol,
              &Bs[(((i << 5) + ldsrow0) << 6)]);
    }
    __syncthreads();
    int arow = ((wm << 6) + (lane & 15)) << 6;   // + mf*16*64
    int brow = ((wn << 6) + (lane & 15)) << 6;
    int koff = ((lane >> 4) << 3);
#pragma unroll
    for (int ks = 0; ks < 2; ++ks) {
      bf16x8 af[4], bf[4];
#pragma unroll
      for (int mf = 0; mf < 4; ++mf)
        af[mf] = *reinterpret_cast<const bf16x8*>(&As[arow + (mf << 10) + (ks << 5) + koff]);
#pragma unroll
      for (int nf = 0; nf < 4; ++nf)
        bf[nf] = *reinterpret_cast<const bf16x8*>(&Bs[brow + (nf << 10) + (ks << 5) + koff]);
#pragma unroll
      for (int mf = 0; mf < 4; ++mf)
#pragma unroll
        for (int nf = 0; nf < 4; ++nf)
          acc[mf][nf] = __builtin_amdgcn_mfma_f32_16x16x32_bf16(af[mf], bf[nf], acc[mf][nf], 0, 0, 0);
    }
    __syncthreads();
  }

  // epilogue
  int cl = lane & 15;
  int rg = (lane >> 4) << 2;
#pragma unroll
  for (int mf = 0; mf < 4; ++mf) {
#pragma unroll
    for (int r = 0; r < 4; ++r) {
      int rr = m0 + (wm << 6) + (mf << 4) + rg + r;
      int ar = (rr / NT_) * T_ + (rr % T_);
      long rbase  = (long)rr * ldc + c0;
      long rbase2 = (long)rr * 256 + c0;
      long abase  = (long)ar * 256 + c0;
#pragma unroll
      for (int nf = 0; nf < 4; ++nf) {
        int gcol = n0 + (wn << 6) + (nf << 4) + cl;
        if (gcol < Nact) {
          float v = acc[mf][nf][r];
          if (bias) v += bias[gcol];
          if (relu) v = fmaxf(v, 0.f);
          if (resb) v += b2f(resb[rbase2 + gcol]);
          if (resf) v += resf[rbase + gcol];
          float e1 = emb1 ? emb1[abase + gcol] : 0.f;
          if (Cf)  Cf[rbase + gcol] = v + e1;
          if (Cb1) Cb1[rbase + gcol] = f2b(v + e1);
          if (Cb2) Cb2[rbase + gcol] = f2b(v + e1 + emb2[abase + gcol]);
        }
      }
    }
  }
}

// ---------------------------------------------------------------------------
// MFMA attention: one block (4 waves) per (bn, h). T=168 -> 11 tiles of 16.
// K staged fragment-linear (gload16), V staged transposed [32][200] (pad ->
// 2-way bank aliasing only). Per wave: query tiles qt = w, w+4, w+8.
// Exact softmax (full row in regs), P via per-wave LDS buffer, PV MFMA,
// normalize at store. O in-place over Q (disjoint (h,row) slices).
// ---------------------------------------------------------------------------
__global__ __launch_bounds__(256) void attn_mfma_kernel(
    const unsigned short* Q, const unsigned short* __restrict__ Kg,
    const unsigned short* __restrict__ V, unsigned short* O) {
  int blk = blockIdx.x;
  int bn = blk >> 3, h = blk & 7;
  int tid = threadIdx.x;
  int lane = tid & 63, w = tid >> 6;

  __shared__ unsigned short Kfr[11 * 512];    // 11 KB fragment-linear K tiles
  __shared__ unsigned short VT[32][200];      // 12.5 KB V^T (dh x key), pad
  __shared__ unsigned short Pb[4][16][200];   // 25 KB per-wave P buffers

  const long hbase = (long)bn * T_ * E_ + h * DH_;
  int l15 = lane & 15, lg = lane >> 4;

  // stage K fragments: tile kt -> Kfr[kt*512 + lane*8 ..], one gload16 each
  for (int kt = w; kt < 11; kt += 4) {
    gload16(Kg + hbase + (long)(kt * 16 + l15) * E_ + (lg << 3), &Kfr[kt * 512]);
  }
  // stage V transposed (coalesced uint4 reads, scalar b16 LDS writes)
  for (int i = tid; i < T_ * 4; i += 256) {
    int t = i >> 2, seg = (i & 3) << 3;
    uint4 vv = *reinterpret_cast<const uint4*>(V + hbase + (long)t * E_ + seg);
    const unsigned short* vs = (const unsigned short*)&vv;
#pragma unroll
    for (int j = 0; j < 8; ++j) VT[seg + j][t] = vs[j];
  }
  for (int i = tid; i < 32 * 32; i += 256) VT[i >> 5][168 + (i & 31)] = 0;
  {
    unsigned short* pflat = &Pb[0][0][0];
    for (int i = tid; i < 64 * 24; i += 256)
      pflat[(i / 24) * 200 + 176 + (i % 24)] = 0;
  }
  __syncthreads();

  const float scale = 0.17677669529663687f;  // 1/sqrt(32)
  unsigned short* Pw = &Pb[w][0][0];

  for (int it = 0; it < 3; ++it) {
    int qt = w + it * 4;
    if (qt > 10) break;
    // Q a-fragment straight from global
    bf16x8 af = *reinterpret_cast<const bf16x8*>(
        Q + hbase + (long)(qt * 16 + l15) * E_ + (lg << 3));
    // S row-block: 11 key tiles
    f32x4 s[11];
#pragma unroll
    for (int kt = 0; kt < 11; ++kt) {
      bf16x8 bf = *reinterpret_cast<const bf16x8*>(&Kfr[kt * 512 + lane * 8]);
      s[kt] = __builtin_amdgcn_mfma_f32_16x16x32_bf16(
          af, bf, (f32x4){0.f, 0.f, 0.f, 0.f}, 0, 0, 0);
    }
    // exact softmax per output row (row = lg*4 + r, cols = key = kt*16+l15)
    bool ok10 = (l15 < 8);  // tile 10 keys 160..175: valid iff l15<8
    float inv_l[4];
#pragma unroll
    for (int r = 0; r < 4; ++r) {
      float mx = -1e30f;
#pragma unroll
      for (int kt = 0; kt < 10; ++kt) mx = fmaxf(mx, s[kt][r] * scale);
      if (ok10) mx = fmaxf(mx, s[10][r] * scale);
#pragma unroll
      for (int off = 1; off < 16; off <<= 1) mx = fmaxf(mx, __shfl_xor(mx, off, 64));
      float pv[11];
      float ls = 0.f;
#pragma unroll
      for (int kt = 0; kt < 11; ++kt) {
        bool valid = (kt < 10) || ok10;
        float p = valid ? __expf(s[kt][r] * scale - mx) : 0.f;
        pv[kt] = p;
        ls += p;
      }
#pragma unroll
      for (int off = 1; off < 16; off <<= 1) ls += __shfl_xor(ls, off, 64);
      inv_l[r] = 1.f / ls;
      int prow = (lg << 2) + r;
#pragma unroll
      for (int kt = 0; kt < 11; ++kt)
        Pw[prow * 200 + kt * 16 + l15] = f2b(pv[kt]);
    }
    asm volatile("s_waitcnt lgkmcnt(0)" ::: "memory");
    // PV: O[16 x 32] = P[16 x 192] @ V[192 x 32]
    f32x4 o0 = (f32x4){0.f, 0.f, 0.f, 0.f};
    f32x4 o1 = (f32x4){0.f, 0.f, 0.f, 0.f};
#pragma unroll
    for (int ks = 0; ks < 6; ++ks) {
      bf16x8 pf = *reinterpret_cast<const bf16x8*>(&Pw[l15 * 200 + ks * 32 + (lg << 3)]);
      bf16x8 v0 = *reinterpret_cast<const bf16x8*>(&VT[l15][ks * 32 + (lg << 3)]);
      bf16x8 v1 = *reinterpret_cast<const bf16x8*>(&VT[16 + l15][ks * 32 + (lg << 3)]);
      o0 = __builtin_amdgcn_mfma_f32_16x16x32_bf16(pf, v0, o0, 0, 0, 0);
      o1 = __builtin_amdgcn_mfma_f32_16x16x32_bf16(pf, v1, o1, 0, 0, 0);
    }
    // normalize + store (only valid query rows)
    int rg = lg << 2;
#pragma unroll
    for (int r = 0; r < 4; ++r) {
      int q = qt * 16 + rg + r;
      if (q < T_) {
        long ob = hbase + (long)q * E_;
        O[ob + l15]      = f2b(o0[r] * inv_l[r]);
        O[ob + 16 + l15] = f2b(o1[r] * inv_l[r]);
      }
    }
  }
}

// ---------------------------------------------------------------------------
// In-place LayerNorm over rows of 256 (f32), optional bf16 copy out.
// ---------------------------------------------------------------------------
__global__ __launch_bounds__(256) void ln_kernel(float* X, const float* __restrict__ g,
                                                 const float* __restrict__ bt,
                                                 unsigned short* bout) {
  long row = blockIdx.x;
  int tid = threadIdx.x;
  float v = X[row * 256 + tid];
  float s = v, s2 = v * v;
#pragma unroll
  for (int off = 32; off > 0; off >>= 1) {
    s += __shfl_down(s, off, 64);
    s2 += __shfl_down(s2, off, 64);
  }
  __shared__ float r1[4], r2[4];
  int w = tid >> 6;
  if ((tid & 63) == 0) { r1[w] = s; r2[w] = s2; }
  __syncthreads();
  float S = r1[0] + r1[1] + r1[2] + r1[3];
  float S2 = r2[0] + r2[1] + r2[2] + r2[3];
  float mean = S * 0.00390625f;
  float var = S2 * 0.00390625f - mean * mean;
  float rs = rsqrtf(var + 1e-5f);
  float o = (v - mean) * rs * g[tid] + bt[tid];
  X[row * 256 + tid] = o;
  if (bout) bout[row * 256 + tid] = f2b(o);
}

// ---------------------------------------------------------------------------
extern "C" void kernel_launch(void* const* d_in, const int* in_sizes, int n_in,
                              void* d_out, int out_size, void* d_ws, size_t ws_size,
                              hipStream_t stream) {
  const float* x      = (const float*)d_in[0];
  const float* locs   = (const float*)d_in[1];
  const float* pos_em = (const float*)d_in[2];
  const float* per_em = (const float*)d_in[3];
  const float* gcn_w  = (const float*)d_in[4];
  const float* gcn_b  = (const float*)d_in[5];
  const float* fc1_w  = (const float*)d_in[6];
  const float* fc1_b  = (const float*)d_in[7];
  const float* wq = (const float*)d_in[8];
  const float* bq = (const float*)d_in[9];
  const float* wk = (const float*)d_in[10];
  const float* bk = (const float*)d_in[11];
  const float* wv = (const float*)d_in[12];
  const float* bv = (const float*)d_in[13];
  const float* wo = (const float*)d_in[14];
  const float* bo = (const float*)d_in[15];
  const float* ln1_g = (const float*)d_in[16];
  const float* ln1_b = (const float*)d_in[17];
  const float* ln2_g = (const float*)d_in[18];
  const float* ln2_b = (const float*)d_in[19];
  const float* ff1_w = (const float*)d_in[20];
  const float* ff1_b = (const float*)d_in[21];
  const float* ff2_w = (const float*)d_in[22];
  const float* ff2_b = (const float*)d_in[23];
  float* out = (float*)d_out;

  // ---- workspace layout ---------------------------------------------------
  const size_t ADJ_BYTES = 1u << 20;            // adjacency (f32, 256KB used)
  const size_t WB_BYTES  = 2u << 20;            // bf16 transposed weights
  const size_t SLOT1 = (size_t)NT_ * E_ * 2;    // 5.5 MB per batch per slot
  int CB = 16;
  while (CB > 1) {
    if (ADJ_BYTES + WB_BYTES + 5 * (size_t)CB * SLOT1 <= ws_size) break;
    CB >>= 1;
  }
  char* ws = (char*)d_ws;
  float* adj = (float*)ws;
  unsigned short* wslab = (unsigned short*)(ws + ADJ_BYTES);
  unsigned short* fc1T = wslab;                 // [256][256]
  unsigned short* wqT  = wslab + 65536;
  unsigned short* wkT  = wslab + 2 * 65536;
  unsigned short* wvT  = wslab + 3 * 65536;
  unsigned short* woT  = wslab + 4 * 65536;
  unsigned short* ff1T = wslab + 5 * 65536;     // [1024][256]
  unsigned short* ff2T = wslab + 5 * 65536 + 262144;  // [256][1024]

  const size_t SLOT = (size_t)CB * SLOT1;
  unsigned short* tokb = (unsigned short*)(ws + ADJ_BYTES + WB_BYTES);
  unsigned short* qkb  = tokb + SLOT / 2;       // slot offsets in ushorts
  unsigned short* qb   = tokb + 2 * (SLOT / 2);
  unsigned short* kb   = tokb + 3 * (SLOT / 2);
  unsigned short* vb   = tokb + 4 * (SLOT / 2);
  unsigned short* G    = qb;                    // GCN hidden until fc1 consumes it
  unsigned short* ffi  = qkb;                   // FF intermediate: slots 1..4
  unsigned short* h1b  = tokb;                  // bf16 copy of LN1 out

  adj_kernel<<<B_, 64, 0, stream>>>(locs, adj);
  convw_kernel<<<(65536 + 255) / 256, 256, 0, stream>>>(fc1_w, fc1T, 248, 248, 256, 256);
  convw_kernel<<<(65536 + 255) / 256, 256, 0, stream>>>(wq, wqT, 256, 256, 256, 256);
  convw_kernel<<<(65536 + 255) / 256, 256, 0, stream>>>(wk, wkT, 256, 256, 256, 256);
  convw_kernel<<<(65536 + 255) / 256, 256, 0, stream>>>(wv, wvT, 256, 256, 256, 256);
  convw_kernel<<<(65536 + 255) / 256, 256, 0, stream>>>(wo, woT, 256, 256, 256, 256);
  convw_kernel<<<(262144 + 255) / 256, 256, 0, stream>>>(ff1_w, ff1T, 256, 1024, 256, 1024);
  convw_kernel<<<(262144 + 255) / 256, 256, 0, stream>>>(ff2_w, ff2T, 1024, 256, 1024, 256);

  for (int b0 = 0; b0 < B_; b0 += CB) {
    const int rows = CB * NT_;      // multiple of 128
    const int MB = rows / 128;
    const float* pos_c = pos_em + (long)b0 * T_ * E_;
    const float* per_c = per_em + (long)b0 * T_ * E_;
    float* out_c = out + (long)b0 * NT_ * E_;

    gcn_kernel<<<CB * T_, 256, 0, stream>>>(x, adj, gcn_w, gcn_b, pos_c, per_c,
                                            G, tokb, qkb, b0);
    // fc1 -> tokb[:,8:256] (+pos) and qkb[:,8:256] (+pos+per)
    {
      dim3 g(MB, 2);
      mfma_gemm<<<g, 256, 0, stream>>>(G, 256, fc1T, 256, 248, fc1_b,
                                       nullptr, tokb, qkb, pos_c, per_c,
                                       nullptr, nullptr, 8, 256, 0);
    }
    // Q, K, V
    {
      dim3 g(MB, 2);
      mfma_gemm<<<g, 256, 0, stream>>>(qkb, 256, wqT, 256, 256, bq,
                                       nullptr, qb, nullptr, nullptr, nullptr,
                                       nullptr, nullptr, 0, 256, 0);
      mfma_gemm<<<g, 256, 0, stream>>>(qkb, 256, wkT, 256, 256, bk,
                                       nullptr, kb, nullptr, nullptr, nullptr,
                                       nullptr, nullptr, 0, 256, 0);
      mfma_gemm<<<g, 256, 0, stream>>>(tokb, 256, wvT, 256, 256, bv,
                                       nullptr, vb, nullptr, nullptr, nullptr,
                                       nullptr, nullptr, 0, 256, 0);
    }
    // attention (O in-place over Q), MFMA version
    attn_mfma_kernel<<<CB * N_ * H_, 256, 0, stream>>>(qb, kb, vb, qb);
    // out_c = tokb + O @ wo + bo ; LN1 in place (+ bf16 copy h1b)
    {
      dim3 g(MB, 2);
      mfma_gemm<<<g, 256, 0, stream>>>(qb, 256, woT, 256, 256, bo,
                                       out_c, nullptr, nullptr, nullptr, nullptr,
                                       tokb, nullptr, 0, 256, 0);
    }
    ln_kernel<<<rows, 256, 0, stream>>>(out_c, ln1_g, ln1_b, h1b);
    // FF1: ffi = relu(h1b @ ff1_w + b)   [rows x 1024 bf16]
    {
      dim3 g(MB, 8);
      mfma_gemm<<<g, 256, 0, stream>>>(h1b, 256, ff1T, 256, 1024, ff1_b,
                                       nullptr, ffi, nullptr, nullptr, nullptr,
                                       nullptr, nullptr, 0, 1024, 1);
    }
    // FF2: out_c = h1 + ffi @ ff2_w + b  (resf aliases Cf, per-cell safe)
    {
      dim3 g(MB, 2);
      mfma_gemm<<<g, 256, 0, stream>>>(ffi, 1024, ff2T, 1024, 256, ff2_b,
                                       out_c, nullptr, nullptr, nullptr, nullptr,
                                       nullptr, out_c, 0, 256, 0);
    }
    ln_kernel<<<rows, 256, 0, stream>>>(out_c, ln2_g, ln2_b, nullptr);
  }
}

// Round 6
// 2122.420 us; speedup vs baseline: 4.6722x; 1.1622x over previous
//
#include <hip/hip_runtime.h>
#include <hip/hip_bf16.h>

// Problem dims
constexpr int B_  = 16;
constexpr int N_  = 64;     // stations
constexpr int T_  = 168;    // seq
constexpr int F_  = 8;      // raw features
constexpr int E_  = 256;    // dmodel
constexpr int H_  = 8;      // heads
constexpr int DH_ = 32;     // head dim
constexpr int NT_ = N_ * T_;           // 10752 (rows per batch)
constexpr int LDQ_ = 768;              // interleaved Q|K|V row stride

typedef __bf16 bf16x8 __attribute__((ext_vector_type(8)));
typedef float  f32x4  __attribute__((ext_vector_type(4)));

__device__ __forceinline__ unsigned short f2b(float f) {
  union { float f; unsigned int u; } v; v.f = f;
  unsigned int r = (v.u + 0x7FFFu + ((v.u >> 16) & 1u)) >> 16;
  return (unsigned short)r;
}
__device__ __forceinline__ float b2f(unsigned short h) {
  union { unsigned int u; float f; } v; v.u = ((unsigned int)h) << 16;
  return v.f;
}
__device__ __forceinline__ void gload16(const void* g, void* l) {
  __builtin_amdgcn_global_load_lds(
      (const __attribute__((address_space(1))) unsigned int*)g,
      (__attribute__((address_space(3))) unsigned int*)l, 16, 0, 0);
}

// ---------------------------------------------------------------------------
// adjacency  a[b][m][n] = 0.5*(w_norm[m][n] + (m==n))
// ---------------------------------------------------------------------------
__global__ void adj_kernel(const float* __restrict__ locs, float* __restrict__ a) {
  int b = blockIdx.x;
  int m = threadIdx.x;  // 64 threads
  __shared__ float lx[64], ly[64];
  lx[m] = locs[(b * 64 + m) * 2 + 0];
  ly[m] = locs[(b * 64 + m) * 2 + 1];
  __syncthreads();
  float x = lx[m], y = ly[m];
  float sum = 0.f;
  for (int n = 0; n < 64; ++n) {
    float dx = x - lx[n], dy = y - ly[n];
    float d = sqrtf(dx * dx + dy * dy + 1e-12f);
    sum += (n == m) ? 0.f : 1.f / d;
  }
  float inv = 0.5f / sum;
  for (int n = 0; n < 64; ++n) {
    float dx = x - lx[n], dy = y - ly[n];
    float d = sqrtf(dx * dx + dy * dy + 1e-12f);
    float w = (n == m) ? 0.5f : inv / d;
    a[(b * 64 + m) * 64 + n] = w;
  }
}

// ---------------------------------------------------------------------------
// weight convert: in f32 [K][N] (ld N) -> outT bf16 [Np][Kp] (ld Kp), zero pad
// ---------------------------------------------------------------------------
__global__ void convw_kernel(const float* __restrict__ in, unsigned short* __restrict__ outT,
                             int K, int N, int Kp, int Np) {
  int idx = blockIdx.x * 256 + threadIdx.x;
  if (idx >= Np * Kp) return;
  int n = idx / Kp, k = idx % Kp;
  float v = (k < K && n < N) ? in[(long)k * N + n] : 0.f;
  outT[idx] = f2b(v);
}

// ---------------------------------------------------------------------------
// GCN front-end for one (b,t) in chunk [b0, b0+CB):
//   G[lrow][0..255]  = relu(xa@gcn_w + gcn_b) bf16 (cols 248..255 = 0)
//   tokb[lrow][0..7] = bf16(x + pos_em);  qkb[lrow][0..7] = bf16(x+pos+per)
// ---------------------------------------------------------------------------
__global__ __launch_bounds__(256) void gcn_kernel(
    const float* __restrict__ x, const float* __restrict__ adj,
    const float* __restrict__ gcn_w, const float* __restrict__ gcn_b,
    const float* __restrict__ pos_em, const float* __restrict__ per_em,
    unsigned short* __restrict__ G, unsigned short* __restrict__ tokb,
    unsigned short* __restrict__ qkb, int b0) {
  int bl = blockIdx.x / T_;
  int t = blockIdx.x % T_;
  int b = b0 + bl;
  int tid = threadIdx.x;
  __shared__ float sX[512];   // x[b,:,t,:]  [64][8]
  __shared__ float sXA[512];  // xa          [64][8]
  const float* adjb = adj + b * 4096;
  for (int i = tid; i < 512; i += 256) {
    int n = i >> 3, f = i & 7;
    sX[i] = x[((long)(b * 64 + n) * T_ + t) * F_ + f];
  }
  __syncthreads();
  for (int i = tid; i < 512; i += 256) {
    int m = i >> 3, f = i & 7;
    float s = 0.f;
    for (int n = 0; n < 64; ++n) s += adjb[(m << 6) + n] * sX[(n << 3) + f];
    sXA[i] = s;
  }
  {
    long pbase = ((long)bl * T_ + t) * E_;
    for (int i = tid; i < 512; i += 256) {
      int m = i >> 3, f = i & 7;
      long lrow = (long)(bl * 64 + m) * T_ + t;
      float base = sX[i] + pos_em[pbase + f];
      tokb[lrow * E_ + f] = f2b(base);
      qkb[lrow * E_ + f]  = f2b(base + per_em[pbase + f]);
    }
  }
  __syncthreads();
  for (int i = tid; i < 64 * 256; i += 256) {
    int m = i >> 8, d = i & 255;
    float v = 0.f;
    if (d < 248) {
      float s = gcn_b[d];
      const float* xam = &sXA[m << 3];
#pragma unroll
      for (int f = 0; f < 8; ++f) s += xam[f] * gcn_w[f * 248 + d];
      v = fmaxf(s, 0.f);
    }
    long lrow = (long)(bl * 64 + m) * T_ + t;
    G[lrow * 256 + d] = f2b(v);
  }
}

// ---------------------------------------------------------------------------
// bf16 MFMA GEMM, 2-phase double-buffered (T3-min) + T2 both-sides swizzle:
//   stage source chunk XOR (l&7)^((l>>3)&7); LDS linear; ds_read XOR (row&7).
// 128x128 tile, BK=64, 4 waves (2x2). One vmcnt(0)+barrier per K-step.
// A [M][lda] bf16, Bt [Npad][K] bf16 (pre-transposed weights), M%128==0.
// ---------------------------------------------------------------------------
__global__ __launch_bounds__(256) void mfma_gemm(
    const unsigned short* __restrict__ A, int lda,
    const unsigned short* __restrict__ Bt, int K, int Nact,
    const float* __restrict__ bias,
    float* Cf, unsigned short* Cb1, unsigned short* Cb2,
    const float* __restrict__ emb1, const float* __restrict__ emb2,
    const unsigned short* __restrict__ resb, const float* resf,
    int c0, int ldc, int relu) {
  __shared__ unsigned short As[2][8192];
  __shared__ unsigned short Bs[2][8192];
  int tid = threadIdx.x;
  int lane = tid & 63, wid = tid >> 6;
  int wm = wid >> 1, wn = wid & 1;
  int m0 = blockIdx.x * 128, n0 = blockIdx.y * 128;
  f32x4 acc[4][4];
#pragma unroll
  for (int i = 0; i < 4; ++i)
#pragma unroll
    for (int j = 0; j < 4; ++j) acc[i][j] = (f32x4){0.f, 0.f, 0.f, 0.f};

  const unsigned short* Ab = A + (long)m0 * lda;
  const unsigned short* Bb = Bt + (long)n0 * K;
  int srow = tid >> 3;                                  // 0..31 global row in 32-row group
  int swcol = (((tid & 7) ^ ((tid >> 3) & 7)) << 3);    // swizzled source col (elems)
  int dst0 = (wid << 3) << 6;                           // wave-uniform LDS dest (ushorts)
  int l15 = lane & 15, lg = lane >> 4;
  int swr = l15 & 7;

  int nk = K >> 6;
  // prologue: stage k-tile 0 into buf 0
#pragma unroll
  for (int i = 0; i < 4; ++i) {
    gload16(Ab + (long)((i << 5) + srow) * lda + swcol, &As[0][(i << 11) + dst0]);
    gload16(Bb + (long)((i << 5) + srow) * K + swcol, &Bs[0][(i << 11) + dst0]);
  }
  __syncthreads();
  int cur = 0;
  for (int kt = 0; kt < nk; ++kt) {
    if (kt + 1 < nk) {
      int k0n = (kt + 1) << 6;
#pragma unroll
      for (int i = 0; i < 4; ++i) {
        gload16(Ab + (long)((i << 5) + srow) * lda + k0n + swcol, &As[cur ^ 1][(i << 11) + dst0]);
        gload16(Bb + (long)((i << 5) + srow) * K + k0n + swcol, &Bs[cur ^ 1][(i << 11) + dst0]);
      }
    }
#pragma unroll
    for (int ks = 0; ks < 2; ++ks) {
      bf16x8 af[4], bf[4];
#pragma unroll
      for (int mf = 0; mf < 4; ++mf) {
        int row = (wm << 6) + (mf << 4) + l15;
        af[mf] = *reinterpret_cast<const bf16x8*>(
            &As[cur][(row << 6) + ((((ks << 2) + lg) ^ swr) << 3)]);
      }
#pragma unroll
      for (int nf = 0; nf < 4; ++nf) {
        int row = (wn << 6) + (nf << 4) + l15;
        bf[nf] = *reinterpret_cast<const bf16x8*>(
            &Bs[cur][(row << 6) + ((((ks << 2) + lg) ^ swr) << 3)]);
      }
#pragma unroll
      for (int mf = 0; mf < 4; ++mf)
#pragma unroll
        for (int nf = 0; nf < 4; ++nf)
          acc[mf][nf] = __builtin_amdgcn_mfma_f32_16x16x32_bf16(af[mf], bf[nf], acc[mf][nf], 0, 0, 0);
    }
    if (kt + 1 < nk) { __syncthreads(); cur ^= 1; }
  }

  // epilogue
  int cl = l15;
  int rg = lg << 2;
#pragma unroll
  for (int mf = 0; mf < 4; ++mf) {
#pragma unroll
    for (int r = 0; r < 4; ++r) {
      int rr = m0 + (wm << 6) + (mf << 4) + rg + r;
      int ar = (rr / NT_) * T_ + (rr % T_);
      long rbase  = (long)rr * ldc + c0;
      long rbase2 = (long)rr * 256 + c0;
      long abase  = (long)ar * 256 + c0;
#pragma unroll
      for (int nf = 0; nf < 4; ++nf) {
        int gcol = n0 + (wn << 6) + (nf << 4) + cl;
        if (gcol < Nact) {
          float v = acc[mf][nf][r];
          if (bias) v += bias[gcol];
          if (relu) v = fmaxf(v, 0.f);
          if (resb) v += b2f(resb[rbase2 + gcol]);
          if (resf) v += resf[rbase + gcol];
          float e1 = emb1 ? emb1[abase + gcol] : 0.f;
          if (Cf)  Cf[rbase + gcol] = v + e1;
          if (Cb1) Cb1[rbase + gcol] = f2b(v + e1);
          if (Cb2) Cb2[rbase + gcol] = f2b(v + e1 + emb2[abase + gcol]);
        }
      }
    }
  }
}

// ---------------------------------------------------------------------------
// MFMA attention: one block (4 waves) per (bn, h), QKV interleaved ld=LDQ_.
// Q at +0, K at +256, V at +512. O in-place over Q slice.
// ---------------------------------------------------------------------------
__global__ __launch_bounds__(256) void attn_mfma_kernel(unsigned short* QKV) {
  int blk = blockIdx.x;
  int bn = blk >> 3, h = blk & 7;
  int tid = threadIdx.x;
  int lane = tid & 63, w = tid >> 6;

  __shared__ unsigned short Kfr[11 * 512];    // fragment-linear K tiles
  __shared__ unsigned short VT[32][200];      // V^T (dh x key), pad
  __shared__ unsigned short Pb[4][16][200];   // per-wave P buffers

  const long qbase = (long)bn * T_ * LDQ_ + h * DH_;
  const unsigned short* Kg = QKV + qbase + 256;
  const unsigned short* V  = QKV + qbase + 512;
  const unsigned short* Q  = QKV + qbase;
  unsigned short* O = QKV + qbase;
  int l15 = lane & 15, lg = lane >> 4;

  for (int kt = w; kt < 11; kt += 4) {
    gload16(Kg + (long)(kt * 16 + l15) * LDQ_ + (lg << 3), &Kfr[kt * 512]);
  }
  for (int i = tid; i < T_ * 4; i += 256) {
    int t = i >> 2, seg = (i & 3) << 3;
    uint4 vv = *reinterpret_cast<const uint4*>(V + (long)t * LDQ_ + seg);
    const unsigned short* vs = (const unsigned short*)&vv;
#pragma unroll
    for (int j = 0; j < 8; ++j) VT[seg + j][t] = vs[j];
  }
  for (int i = tid; i < 32 * 32; i += 256) VT[i >> 5][168 + (i & 31)] = 0;
  {
    unsigned short* pflat = &Pb[0][0][0];
    for (int i = tid; i < 64 * 24; i += 256)
      pflat[(i / 24) * 200 + 176 + (i % 24)] = 0;
  }
  __syncthreads();

  const float scale = 0.17677669529663687f;  // 1/sqrt(32)
  unsigned short* Pw = &Pb[w][0][0];

  for (int it = 0; it < 3; ++it) {
    int qt = w + it * 4;
    if (qt > 10) break;
    bf16x8 af = *reinterpret_cast<const bf16x8*>(
        Q + (long)(qt * 16 + l15) * LDQ_ + (lg << 3));
    f32x4 s[11];
#pragma unroll
    for (int kt = 0; kt < 11; ++kt) {
      bf16x8 bf = *reinterpret_cast<const bf16x8*>(&Kfr[kt * 512 + lane * 8]);
      s[kt] = __builtin_amdgcn_mfma_f32_16x16x32_bf16(
          af, bf, (f32x4){0.f, 0.f, 0.f, 0.f}, 0, 0, 0);
    }
    bool ok10 = (l15 < 8);
    float inv_l[4];
#pragma unroll
    for (int r = 0; r < 4; ++r) {
      float mx = -1e30f;
#pragma unroll
      for (int kt = 0; kt < 10; ++kt) mx = fmaxf(mx, s[kt][r] * scale);
      if (ok10) mx = fmaxf(mx, s[10][r] * scale);
#pragma unroll
      for (int off = 1; off < 16; off <<= 1) mx = fmaxf(mx, __shfl_xor(mx, off, 64));
      float pv[11];
      float ls = 0.f;
#pragma unroll
      for (int kt = 0; kt < 11; ++kt) {
        bool valid = (kt < 10) || ok10;
        float p = valid ? __expf(s[kt][r] * scale - mx) : 0.f;
        pv[kt] = p;
        ls += p;
      }
#pragma unroll
      for (int off = 1; off < 16; off <<= 1) ls += __shfl_xor(ls, off, 64);
      inv_l[r] = 1.f / ls;
      int prow = (lg << 2) + r;
#pragma unroll
      for (int kt = 0; kt < 11; ++kt)
        Pw[prow * 200 + kt * 16 + l15] = f2b(pv[kt]);
    }
    asm volatile("s_waitcnt lgkmcnt(0)" ::: "memory");
    __builtin_amdgcn_sched_barrier(0);
    f32x4 o0 = (f32x4){0.f, 0.f, 0.f, 0.f};
    f32x4 o1 = (f32x4){0.f, 0.f, 0.f, 0.f};
#pragma unroll
    for (int ks = 0; ks < 6; ++ks) {
      bf16x8 pf = *reinterpret_cast<const bf16x8*>(&Pw[l15 * 200 + ks * 32 + (lg << 3)]);
      bf16x8 v0 = *reinterpret_cast<const bf16x8*>(&VT[l15][ks * 32 + (lg << 3)]);
      bf16x8 v1 = *reinterpret_cast<const bf16x8*>(&VT[16 + l15][ks * 32 + (lg << 3)]);
      o0 = __builtin_amdgcn_mfma_f32_16x16x32_bf16(pf, v0, o0, 0, 0, 0);
      o1 = __builtin_amdgcn_mfma_f32_16x16x32_bf16(pf, v1, o1, 0, 0, 0);
    }
    int rg = lg << 2;
#pragma unroll
    for (int r = 0; r < 4; ++r) {
      int q = qt * 16 + rg + r;
      if (q < T_) {
        long ob = (long)q * LDQ_;
        O[ob + l15]      = f2b(o0[r] * inv_l[r]);
        O[ob + 16 + l15] = f2b(o1[r] * inv_l[r]);
      }
    }
  }
}

// ---------------------------------------------------------------------------
// LayerNorm over rows of 256, bf16 input (ld ldx), 4 rows/block, 64 lanes/row.
// Outputs: optional bf16 (ld 256) and/or f32 (ld 256).
// ---------------------------------------------------------------------------
__global__ __launch_bounds__(256) void ln_bf_kernel(
    const unsigned short* __restrict__ X, int ldx,
    const float* __restrict__ g, const float* __restrict__ bt,
    unsigned short* __restrict__ bout, float* __restrict__ fout) {
  long row = (long)blockIdx.x * 4 + (threadIdx.x >> 6);
  int lane = threadIdx.x & 63;
  ushort4 xv = *reinterpret_cast<const ushort4*>(X + row * ldx + (lane << 2));
  float v0 = b2f(xv.x), v1 = b2f(xv.y), v2 = b2f(xv.z), v3 = b2f(xv.w);
  float s = v0 + v1 + v2 + v3;
  float s2 = v0 * v0 + v1 * v1 + v2 * v2 + v3 * v3;
#pragma unroll
  for (int off = 32; off > 0; off >>= 1) {
    s += __shfl_xor(s, off, 64);
    s2 += __shfl_xor(s2, off, 64);
  }
  float mean = s * 0.00390625f;
  float var = s2 * 0.00390625f - mean * mean;
  float rs = rsqrtf(var + 1e-5f);
  float4 gv = *reinterpret_cast<const float4*>(g + (lane << 2));
  float4 bv = *reinterpret_cast<const float4*>(bt + (lane << 2));
  float o0 = (v0 - mean) * rs * gv.x + bv.x;
  float o1 = (v1 - mean) * rs * gv.y + bv.y;
  float o2 = (v2 - mean) * rs * gv.z + bv.z;
  float o3 = (v3 - mean) * rs * gv.w + bv.w;
  if (bout) {
    ushort4 ov = {f2b(o0), f2b(o1), f2b(o2), f2b(o3)};
    *reinterpret_cast<ushort4*>(bout + row * 256 + (lane << 2)) = ov;
  }
  if (fout) {
    float4 fo = {o0, o1, o2, o3};
    *reinterpret_cast<float4*>(fout + row * 256 + (lane << 2)) = fo;
  }
}

// ---------------------------------------------------------------------------
extern "C" void kernel_launch(void* const* d_in, const int* in_sizes, int n_in,
                              void* d_out, int out_size, void* d_ws, size_t ws_size,
                              hipStream_t stream) {
  const float* x      = (const float*)d_in[0];
  const float* locs   = (const float*)d_in[1];
  const float* pos_em = (const float*)d_in[2];
  const float* per_em = (const float*)d_in[3];
  const float* gcn_w  = (const float*)d_in[4];
  const float* gcn_b  = (const float*)d_in[5];
  const float* fc1_w  = (const float*)d_in[6];
  const float* fc1_b  = (const float*)d_in[7];
  const float* wq = (const float*)d_in[8];
  const float* bq = (const float*)d_in[9];
  const float* wk = (const float*)d_in[10];
  const float* bk = (const float*)d_in[11];
  const float* wv = (const float*)d_in[12];
  const float* bv = (const float*)d_in[13];
  const float* wo = (const float*)d_in[14];
  const float* bo = (const float*)d_in[15];
  const float* ln1_g = (const float*)d_in[16];
  const float* ln1_b = (const float*)d_in[17];
  const float* ln2_g = (const float*)d_in[18];
  const float* ln2_b = (const float*)d_in[19];
  const float* ff1_w = (const float*)d_in[20];
  const float* ff1_b = (const float*)d_in[21];
  const float* ff2_w = (const float*)d_in[22];
  const float* ff2_b = (const float*)d_in[23];
  float* out = (float*)d_out;

  // ---- workspace layout ---------------------------------------------------
  const size_t ADJ_BYTES = 1u << 20;
  const size_t WB_BYTES  = 2u << 20;
  int CB = 16;
  while (CB > 1) {
    if (ADJ_BYTES + WB_BYTES + (size_t)CB * NT_ * 2560 <= ws_size) break;
    CB >>= 1;
  }
  char* ws = (char*)d_ws;
  float* adj = (float*)ws;
  unsigned short* wslab = (unsigned short*)(ws + ADJ_BYTES);
  unsigned short* fc1T  = wslab;                        // [256][256]
  unsigned short* wqkT  = wslab + 65536;                // [512][256] (wq|wk)
  unsigned short* wkT   = wslab + 2 * 65536;
  unsigned short* wvT   = wslab + 3 * 65536;
  unsigned short* woT   = wslab + 4 * 65536;
  unsigned short* ff1T  = wslab + 5 * 65536;            // [1024][256]
  unsigned short* ff2T  = wslab + 5 * 65536 + 262144;   // [256][1024]
  float* bqk = (float*)(ws + ADJ_BYTES + 1900544);      // [512] concat bias

  unsigned short* tokb = (unsigned short*)(ws + ADJ_BYTES + WB_BYTES);
  unsigned short* qkb  = tokb + (size_t)CB * NT_ * 256;
  unsigned short* qkv  = qkb + (size_t)CB * NT_ * 256;  // [rows][768] Q|K|V
  unsigned short* ffi  = qkb;                           // [rows][1024] (over qkb+qkv)
  unsigned short* h1b  = tokb;                          // bf16 h1 (over tokb)
  unsigned short* aob  = qkv + 256;                     // pre-LN1 (over K region, ld 768)

  adj_kernel<<<B_, 64, 0, stream>>>(locs, adj);
  convw_kernel<<<256, 256, 0, stream>>>(fc1_w, fc1T, 248, 248, 256, 256);
  convw_kernel<<<256, 256, 0, stream>>>(wq, wqkT, 256, 256, 256, 256);
  convw_kernel<<<256, 256, 0, stream>>>(wk, wkT, 256, 256, 256, 256);
  convw_kernel<<<256, 256, 0, stream>>>(wv, wvT, 256, 256, 256, 256);
  convw_kernel<<<256, 256, 0, stream>>>(wo, woT, 256, 256, 256, 256);
  convw_kernel<<<1024, 256, 0, stream>>>(ff1_w, ff1T, 256, 1024, 256, 1024);
  convw_kernel<<<1024, 256, 0, stream>>>(ff2_w, ff2T, 1024, 256, 1024, 256);
  hipMemcpyAsync(bqk, bq, 256 * sizeof(float), hipMemcpyDeviceToDevice, stream);
  hipMemcpyAsync(bqk + 256, bk, 256 * sizeof(float), hipMemcpyDeviceToDevice, stream);

  for (int b0 = 0; b0 < B_; b0 += CB) {
    const int rows = CB * NT_;      // multiple of 128
    const int MB = rows / 128;
    const float* pos_c = pos_em + (long)b0 * T_ * E_;
    const float* per_c = per_em + (long)b0 * T_ * E_;
    float* out_c = out + (long)b0 * NT_ * E_;
    unsigned short* G = qkv;        // GCN hidden lives in qkv area until consumed

    gcn_kernel<<<CB * T_, 256, 0, stream>>>(x, adj, gcn_w, gcn_b, pos_c, per_c,
                                            G, tokb, qkb, b0);
    // fc1 -> tokb[:,8:256] (+pos) and qkb[:,8:256] (+pos+per)
    {
      dim3 g(MB, 2);
      mfma_gemm<<<g, 256, 0, stream>>>(G, 256, fc1T, 256, 248, fc1_b,
                                       nullptr, tokb, qkb, pos_c, per_c,
                                       nullptr, nullptr, 8, 256, 0);
    }
    // fused Q|K (N=512) from qkb -> qkv[:, 0:512]
    {
      dim3 g(MB, 4);
      mfma_gemm<<<g, 256, 0, stream>>>(qkb, 256, wqkT, 256, 512, bqk,
                                       nullptr, qkv, nullptr, nullptr, nullptr,
                                       nullptr, nullptr, 0, LDQ_, 0);
    }
    // V from tokb -> qkv[:, 512:768]
    {
      dim3 g(MB, 2);
      mfma_gemm<<<g, 256, 0, stream>>>(tokb, 256, wvT, 256, 256, bv,
                                       nullptr, qkv, nullptr, nullptr, nullptr,
                                       nullptr, nullptr, 512, LDQ_, 0);
    }
    // attention (O in-place over Q slice of qkv)
    attn_mfma_kernel<<<CB * N_ * H_, 256, 0, stream>>>(qkv);
    // aob = tokb + O @ wo + bo   (bf16, over dead K region, ld 768)
    {
      dim3 g(MB, 2);
      mfma_gemm<<<g, 256, 0, stream>>>(qkv, LDQ_, woT, 256, 256, bo,
                                       nullptr, aob, nullptr, nullptr, nullptr,
                                       tokb, nullptr, 0, LDQ_, 0);
    }
    // LN1: aob -> h1b (bf16, over tokb)
    ln_bf_kernel<<<rows / 4, 256, 0, stream>>>(aob, LDQ_, ln1_g, ln1_b, h1b, nullptr);
    // FF1: ffi = relu(h1b @ ff1_w + b)
    {
      dim3 g(MB, 8);
      mfma_gemm<<<g, 256, 0, stream>>>(h1b, 256, ff1T, 256, 1024, ff1_b,
                                       nullptr, ffi, nullptr, nullptr, nullptr,
                                       nullptr, nullptr, 0, 1024, 1);
    }
    // FF2: h1b = h1 + ffi @ ff2_w + b  (bf16, element-wise safe aliasing)
    {
      dim3 g(MB, 2);
      mfma_gemm<<<g, 256, 0, stream>>>(ffi, 1024, ff2T, 1024, 256, ff2_b,
                                       nullptr, h1b, nullptr, nullptr, nullptr,
                                       h1b, nullptr, 0, 256, 0);
    }
    // LN2: h1b -> out (f32)
    ln_bf_kernel<<<rows / 4, 256, 0, stream>>>(h1b, 256, ln2_g, ln2_b, nullptr, out_c);
  }
}

// Round 7
// 2034.043 us; speedup vs baseline: 4.8752x; 1.0434x over previous
//
#include <hip/hip_runtime.h>
#include <hip/hip_bf16.h>

// Problem dims
constexpr int B_  = 16;
constexpr int N_  = 64;     // stations
constexpr int T_  = 168;    // seq
constexpr int F_  = 8;      // raw features
constexpr int E_  = 256;    // dmodel
constexpr int H_  = 8;      // heads
constexpr int DH_ = 32;     // head dim
constexpr int NT_ = N_ * T_;           // 10752 (rows per batch)
constexpr int LDQ_ = 768;              // interleaved Q|K|V row stride

typedef __bf16 bf16x8 __attribute__((ext_vector_type(8)));
typedef float  f32x4  __attribute__((ext_vector_type(4)));

__device__ __forceinline__ unsigned short f2b(float f) {
  union { float f; unsigned int u; } v; v.f = f;
  unsigned int r = (v.u + 0x7FFFu + ((v.u >> 16) & 1u)) >> 16;
  return (unsigned short)r;
}
__device__ __forceinline__ float b2f(unsigned short h) {
  union { unsigned int u; float f; } v; v.u = ((unsigned int)h) << 16;
  return v.f;
}
__device__ __forceinline__ void gload16(const void* g, void* l) {
  __builtin_amdgcn_global_load_lds(
      (const __attribute__((address_space(1))) unsigned int*)g,
      (__attribute__((address_space(3))) unsigned int*)l, 16, 0, 0);
}

// ---------------------------------------------------------------------------
// adjacency  a[b][m][n] = 0.5*(w_norm[m][n] + (m==n))
// ---------------------------------------------------------------------------
__global__ void adj_kernel(const float* __restrict__ locs, float* __restrict__ a) {
  int b = blockIdx.x;
  int m = threadIdx.x;  // 64 threads
  __shared__ float lx[64], ly[64];
  lx[m] = locs[(b * 64 + m) * 2 + 0];
  ly[m] = locs[(b * 64 + m) * 2 + 1];
  __syncthreads();
  float x = lx[m], y = ly[m];
  float sum = 0.f;
  for (int n = 0; n < 64; ++n) {
    float dx = x - lx[n], dy = y - ly[n];
    float d = sqrtf(dx * dx + dy * dy + 1e-12f);
    sum += (n == m) ? 0.f : 1.f / d;
  }
  float inv = 0.5f / sum;
  for (int n = 0; n < 64; ++n) {
    float dx = x - lx[n], dy = y - ly[n];
    float d = sqrtf(dx * dx + dy * dy + 1e-12f);
    float w = (n == m) ? 0.5f : inv / d;
    a[(b * 64 + m) * 64 + n] = w;
  }
}

// ---------------------------------------------------------------------------
// weight convert: in f32 [K][N] (ld N) -> outT bf16 [Np][Kp] (ld Kp), zero pad
// ---------------------------------------------------------------------------
__global__ void convw_kernel(const float* __restrict__ in, unsigned short* __restrict__ outT,
                             int K, int N, int Kp, int Np) {
  int idx = blockIdx.x * 256 + threadIdx.x;
  if (idx >= Np * Kp) return;
  int n = idx / Kp, k = idx % Kp;
  float v = (k < K && n < N) ? in[(long)k * N + n] : 0.f;
  outT[idx] = f2b(v);
}

// ---------------------------------------------------------------------------
// GCN front-end for one (b,t) in chunk [b0, b0+CB):
//   G[lrow][0..255]  = relu(xa@gcn_w + gcn_b) bf16 (cols 248..255 = 0)
//   tokb[lrow][0..7] = bf16(x + pos_em);  qkb[lrow][0..7] = bf16(x+pos+per)
// ---------------------------------------------------------------------------
__global__ __launch_bounds__(256) void gcn_kernel(
    const float* __restrict__ x, const float* __restrict__ adj,
    const float* __restrict__ gcn_w, const float* __restrict__ gcn_b,
    const float* __restrict__ pos_em, const float* __restrict__ per_em,
    unsigned short* __restrict__ G, unsigned short* __restrict__ tokb,
    unsigned short* __restrict__ qkb, int b0) {
  int bl = blockIdx.x / T_;
  int t = blockIdx.x % T_;
  int b = b0 + bl;
  int tid = threadIdx.x;
  __shared__ float sX[512];   // x[b,:,t,:]  [64][8]
  __shared__ float sXA[512];  // xa          [64][8]
  const float* adjb = adj + b * 4096;
  for (int i = tid; i < 512; i += 256) {
    int n = i >> 3, f = i & 7;
    sX[i] = x[((long)(b * 64 + n) * T_ + t) * F_ + f];
  }
  __syncthreads();
  for (int i = tid; i < 512; i += 256) {
    int m = i >> 3, f = i & 7;
    float s = 0.f;
    for (int n = 0; n < 64; ++n) s += adjb[(m << 6) + n] * sX[(n << 3) + f];
    sXA[i] = s;
  }
  {
    long pbase = ((long)bl * T_ + t) * E_;
    for (int i = tid; i < 512; i += 256) {
      int m = i >> 3, f = i & 7;
      long lrow = (long)(bl * 64 + m) * T_ + t;
      float base = sX[i] + pos_em[pbase + f];
      tokb[lrow * E_ + f] = f2b(base);
      qkb[lrow * E_ + f]  = f2b(base + per_em[pbase + f]);
    }
  }
  __syncthreads();
  for (int i = tid; i < 64 * 256; i += 256) {
    int m = i >> 8, d = i & 255;
    float v = 0.f;
    if (d < 248) {
      float s = gcn_b[d];
      const float* xam = &sXA[m << 3];
#pragma unroll
      for (int f = 0; f < 8; ++f) s += xam[f] * gcn_w[f * 248 + d];
      v = fmaxf(s, 0.f);
    }
    long lrow = (long)(bl * 64 + m) * T_ + t;
    G[lrow * 256 + d] = f2b(v);
  }
}

// ---------------------------------------------------------------------------
// bf16 MFMA GEMM, 256x256 tile, BK=64, 8 waves (2M x 4N), 512 threads,
// 128 KB double-buffered LDS, COUNTED-vmcnt pipeline (T3+T4):
//   per K-tile: STAGE(t+1) -> s_waitcnt vmcnt(8) -> s_barrier ->
//               64 MFMA (setprio 1) -> s_barrier.   Never vmcnt(0) mid-loop.
// T2 both-sides swizzle: source col ^ (row&7) pre-permuted, ds_read XOR same.
// A [M][lda] bf16 (M%256==0), Bt [Npad][K] bf16 (Npad%256==0, K%64==0).
// Epilogue per cell (gcol<Nact): v=acc+bias, relu, +resb(bf16), +resf(f32),
//   e1/e2 embeddings (ar-indexed): Cf=v+e1 (f32); Cb1=bf16(v+e1); Cb2=bf16(v+e1+e2)
// ---------------------------------------------------------------------------
__global__ __launch_bounds__(512, 2) void mfma_gemm(
    const unsigned short* __restrict__ A, int lda,
    const unsigned short* __restrict__ Bt, int K, int Nact,
    const float* __restrict__ bias,
    float* Cf, unsigned short* Cb1, unsigned short* Cb2,
    const float* __restrict__ emb1, const float* __restrict__ emb2,
    const unsigned short* __restrict__ resb, const float* resf,
    int c0, int ldc, int relu) {
  __shared__ unsigned short As[2][16384];   // [256 rows][64 k] per buffer
  __shared__ unsigned short Bs[2][16384];
  int tid = threadIdx.x;
  int lane = tid & 63, wid = tid >> 6;      // 8 waves
  int wm = wid >> 2, wn = wid & 3;          // 2M x 4N
  int m0 = blockIdx.x * 256, n0 = blockIdx.y * 256;
  f32x4 acc[8][4];
#pragma unroll
  for (int i = 0; i < 8; ++i)
#pragma unroll
    for (int j = 0; j < 4; ++j) acc[i][j] = (f32x4){0.f, 0.f, 0.f, 0.f};

  const unsigned short* Ab = A + (long)m0 * lda;
  const unsigned short* Bb = Bt + (long)n0 * K;
  int rsub = lane >> 3;                     // 0..7 row-within-8
  int swcol = (((lane & 7) ^ rsub) << 3);   // pre-swizzled source col (elems)
  int l15 = lane & 15, lg = lane >> 4;

  int nk = K >> 6;
  // stage K-tile kt into buffer b: per wave 4 A-chunks + 4 B-chunks of 8 rows
#define STAGE(kt, b)                                                          \
  {                                                                           \
    int k0s = (kt) << 6;                                                      \
    _Pragma("unroll")                                                         \
    for (int j = 0; j < 4; ++j) {                                             \
      int row = (j << 6) + (wid << 3);                                        \
      gload16(Ab + (long)(row + rsub) * lda + k0s + swcol, &As[b][row << 6]); \
      gload16(Bb + (long)(row + rsub) * K + k0s + swcol, &Bs[b][row << 6]);   \
    }                                                                         \
  }

  STAGE(0, 0);
  for (int kt = 0; kt < nk; ++kt) {
    int cur = kt & 1;
    if (kt + 1 < nk) {
      STAGE(kt + 1, cur ^ 1);
      asm volatile("s_waitcnt vmcnt(8)" ::: "memory");
    } else {
      asm volatile("s_waitcnt vmcnt(0)" ::: "memory");
    }
    __builtin_amdgcn_sched_barrier(0);
    __builtin_amdgcn_s_barrier();
    __builtin_amdgcn_s_setprio(1);
#pragma unroll
    for (int ks = 0; ks < 2; ++ks) {
      bf16x8 bf[4];
#pragma unroll
      for (int nf = 0; nf < 4; ++nf) {
        int row = (wn << 6) + (nf << 4) + l15;
        bf[nf] = *reinterpret_cast<const bf16x8*>(
            &Bs[cur][(row << 6) + ((((ks << 2) + lg) ^ (row & 7)) << 3)]);
      }
#pragma unroll
      for (int mf = 0; mf < 8; ++mf) {
        int row = (wm << 7) + (mf << 4) + l15;
        bf16x8 af = *reinterpret_cast<const bf16x8*>(
            &As[cur][(row << 6) + ((((ks << 2) + lg) ^ (row & 7)) << 3)]);
#pragma unroll
        for (int nf = 0; nf < 4; ++nf)
          acc[mf][nf] = __builtin_amdgcn_mfma_f32_16x16x32_bf16(af, bf[nf], acc[mf][nf], 0, 0, 0);
      }
    }
    __builtin_amdgcn_s_setprio(0);
    __builtin_amdgcn_s_barrier();
  }
#undef STAGE

  // epilogue
  int cl = l15;
  int rg = lg << 2;
#pragma unroll
  for (int mf = 0; mf < 8; ++mf) {
#pragma unroll
    for (int r = 0; r < 4; ++r) {
      int rr = m0 + (wm << 7) + (mf << 4) + rg + r;
      int ar = (rr / NT_) * T_ + (rr % T_);
      long rbase  = (long)rr * ldc + c0;
      long rbase2 = (long)rr * 256 + c0;
      long abase  = (long)ar * 256 + c0;
#pragma unroll
      for (int nf = 0; nf < 4; ++nf) {
        int gcol = n0 + (wn << 6) + (nf << 4) + cl;
        if (gcol < Nact) {
          float v = acc[mf][nf][r];
          if (bias) v += bias[gcol];
          if (relu) v = fmaxf(v, 0.f);
          if (resb) v += b2f(resb[rbase2 + gcol]);
          if (resf) v += resf[rbase + gcol];
          float e1 = emb1 ? emb1[abase + gcol] : 0.f;
          if (Cf)  Cf[rbase + gcol] = v + e1;
          if (Cb1) Cb1[rbase + gcol] = f2b(v + e1);
          if (Cb2) Cb2[rbase + gcol] = f2b(v + e1 + emb2[abase + gcol]);
        }
      }
    }
  }
}

// ---------------------------------------------------------------------------
// MFMA attention: one block (4 waves) per (bn, h), QKV interleaved ld=LDQ_.
// Q at +0, K at +256, V at +512. O in-place over Q slice.
// ---------------------------------------------------------------------------
__global__ __launch_bounds__(256) void attn_mfma_kernel(unsigned short* QKV) {
  int blk = blockIdx.x;
  int bn = blk >> 3, h = blk & 7;
  int tid = threadIdx.x;
  int lane = tid & 63, w = tid >> 6;

  __shared__ unsigned short Kfr[11 * 512];    // fragment-linear K tiles
  __shared__ unsigned short VT[32][200];      // V^T (dh x key), pad
  __shared__ unsigned short Pb[4][16][200];   // per-wave P buffers

  const long qbase = (long)bn * T_ * LDQ_ + h * DH_;
  const unsigned short* Kg = QKV + qbase + 256;
  const unsigned short* V  = QKV + qbase + 512;
  const unsigned short* Q  = QKV + qbase;
  unsigned short* O = QKV + qbase;
  int l15 = lane & 15, lg = lane >> 4;

  for (int kt = w; kt < 11; kt += 4) {
    gload16(Kg + (long)(kt * 16 + l15) * LDQ_ + (lg << 3), &Kfr[kt * 512]);
  }
  for (int i = tid; i < T_ * 4; i += 256) {
    int t = i >> 2, seg = (i & 3) << 3;
    uint4 vv = *reinterpret_cast<const uint4*>(V + (long)t * LDQ_ + seg);
    const unsigned short* vs = (const unsigned short*)&vv;
#pragma unroll
    for (int j = 0; j < 8; ++j) VT[seg + j][t] = vs[j];
  }
  for (int i = tid; i < 32 * 32; i += 256) VT[i >> 5][168 + (i & 31)] = 0;
  {
    unsigned short* pflat = &Pb[0][0][0];
    for (int i = tid; i < 64 * 24; i += 256)
      pflat[(i / 24) * 200 + 176 + (i % 24)] = 0;
  }
  __syncthreads();

  const float scale = 0.17677669529663687f;  // 1/sqrt(32)
  unsigned short* Pw = &Pb[w][0][0];

  for (int it = 0; it < 3; ++it) {
    int qt = w + it * 4;
    if (qt > 10) break;
    bf16x8 af = *reinterpret_cast<const bf16x8*>(
        Q + (long)(qt * 16 + l15) * LDQ_ + (lg << 3));
    f32x4 s[11];
#pragma unroll
    for (int kt = 0; kt < 11; ++kt) {
      bf16x8 bf = *reinterpret_cast<const bf16x8*>(&Kfr[kt * 512 + lane * 8]);
      s[kt] = __builtin_amdgcn_mfma_f32_16x16x32_bf16(
          af, bf, (f32x4){0.f, 0.f, 0.f, 0.f}, 0, 0, 0);
    }
    bool ok10 = (l15 < 8);
    float inv_l[4];
#pragma unroll
    for (int r = 0; r < 4; ++r) {
      float mx = -1e30f;
#pragma unroll
      for (int kt = 0; kt < 10; ++kt) mx = fmaxf(mx, s[kt][r] * scale);
      if (ok10) mx = fmaxf(mx, s[10][r] * scale);
#pragma unroll
      for (int off = 1; off < 16; off <<= 1) mx = fmaxf(mx, __shfl_xor(mx, off, 64));
      float pv[11];
      float ls = 0.f;
#pragma unroll
      for (int kt = 0; kt < 11; ++kt) {
        bool valid = (kt < 10) || ok10;
        float p = valid ? __expf(s[kt][r] * scale - mx) : 0.f;
        pv[kt] = p;
        ls += p;
      }
#pragma unroll
      for (int off = 1; off < 16; off <<= 1) ls += __shfl_xor(ls, off, 64);
      inv_l[r] = 1.f / ls;
      int prow = (lg << 2) + r;
#pragma unroll
      for (int kt = 0; kt < 11; ++kt)
        Pw[prow * 200 + kt * 16 + l15] = f2b(pv[kt]);
    }
    asm volatile("s_waitcnt lgkmcnt(0)" ::: "memory");
    __builtin_amdgcn_sched_barrier(0);
    f32x4 o0 = (f32x4){0.f, 0.f, 0.f, 0.f};
    f32x4 o1 = (f32x4){0.f, 0.f, 0.f, 0.f};
#pragma unroll
    for (int ks = 0; ks < 6; ++ks) {
      bf16x8 pf = *reinterpret_cast<const bf16x8*>(&Pw[l15 * 200 + ks * 32 + (lg << 3)]);
      bf16x8 v0 = *reinterpret_cast<const bf16x8*>(&VT[l15][ks * 32 + (lg << 3)]);
      bf16x8 v1 = *reinterpret_cast<const bf16x8*>(&VT[16 + l15][ks * 32 + (lg << 3)]);
      o0 = __builtin_amdgcn_mfma_f32_16x16x32_bf16(pf, v0, o0, 0, 0, 0);
      o1 = __builtin_amdgcn_mfma_f32_16x16x32_bf16(pf, v1, o1, 0, 0, 0);
    }
    int rg = lg << 2;
#pragma unroll
    for (int r = 0; r < 4; ++r) {
      int q = qt * 16 + rg + r;
      if (q < T_) {
        long ob = (long)q * LDQ_;
        O[ob + l15]      = f2b(o0[r] * inv_l[r]);
        O[ob + 16 + l15] = f2b(o1[r] * inv_l[r]);
      }
    }
  }
}

// ---------------------------------------------------------------------------
// LayerNorm over rows of 256, bf16 input (ld ldx), 4 rows/block, 64 lanes/row.
// ---------------------------------------------------------------------------
__global__ __launch_bounds__(256) void ln_bf_kernel(
    const unsigned short* __restrict__ X, int ldx,
    const float* __restrict__ g, const float* __restrict__ bt,
    unsigned short* __restrict__ bout, float* __restrict__ fout) {
  long row = (long)blockIdx.x * 4 + (threadIdx.x >> 6);
  int lane = threadIdx.x & 63;
  ushort4 xv = *reinterpret_cast<const ushort4*>(X + row * ldx + (lane << 2));
  float v0 = b2f(xv.x), v1 = b2f(xv.y), v2 = b2f(xv.z), v3 = b2f(xv.w);
  float s = v0 + v1 + v2 + v3;
  float s2 = v0 * v0 + v1 * v1 + v2 * v2 + v3 * v3;
#pragma unroll
  for (int off = 32; off > 0; off >>= 1) {
    s += __shfl_xor(s, off, 64);
    s2 += __shfl_xor(s2, off, 64);
  }
  float mean = s * 0.00390625f;
  float var = s2 * 0.00390625f - mean * mean;
  float rs = rsqrtf(var + 1e-5f);
  float4 gv = *reinterpret_cast<const float4*>(g + (lane << 2));
  float4 bv = *reinterpret_cast<const float4*>(bt + (lane << 2));
  float o0 = (v0 - mean) * rs * gv.x + bv.x;
  float o1 = (v1 - mean) * rs * gv.y + bv.y;
  float o2 = (v2 - mean) * rs * gv.z + bv.z;
  float o3 = (v3 - mean) * rs * gv.w + bv.w;
  if (bout) {
    ushort4 ov = {f2b(o0), f2b(o1), f2b(o2), f2b(o3)};
    *reinterpret_cast<ushort4*>(bout + row * 256 + (lane << 2)) = ov;
  }
  if (fout) {
    float4 fo = {o0, o1, o2, o3};
    *reinterpret_cast<float4*>(fout + row * 256 + (lane << 2)) = fo;
  }
}

// ---------------------------------------------------------------------------
extern "C" void kernel_launch(void* const* d_in, const int* in_sizes, int n_in,
                              void* d_out, int out_size, void* d_ws, size_t ws_size,
                              hipStream_t stream) {
  const float* x      = (const float*)d_in[0];
  const float* locs   = (const float*)d_in[1];
  const float* pos_em = (const float*)d_in[2];
  const float* per_em = (const float*)d_in[3];
  const float* gcn_w  = (const float*)d_in[4];
  const float* gcn_b  = (const float*)d_in[5];
  const float* fc1_w  = (const float*)d_in[6];
  const float* fc1_b  = (const float*)d_in[7];
  const float* wq = (const float*)d_in[8];
  const float* bq = (const float*)d_in[9];
  const float* wk = (const float*)d_in[10];
  const float* bk = (const float*)d_in[11];
  const float* wv = (const float*)d_in[12];
  const float* bv = (const float*)d_in[13];
  const float* wo = (const float*)d_in[14];
  const float* bo = (const float*)d_in[15];
  const float* ln1_g = (const float*)d_in[16];
  const float* ln1_b = (const float*)d_in[17];
  const float* ln2_g = (const float*)d_in[18];
  const float* ln2_b = (const float*)d_in[19];
  const float* ff1_w = (const float*)d_in[20];
  const float* ff1_b = (const float*)d_in[21];
  const float* ff2_w = (const float*)d_in[22];
  const float* ff2_b = (const float*)d_in[23];
  float* out = (float*)d_out;

  // ---- workspace layout ---------------------------------------------------
  const size_t ADJ_BYTES = 1u << 20;
  const size_t WB_BYTES  = 2u << 20;
  int CB = 16;
  while (CB > 1) {
    if (ADJ_BYTES + WB_BYTES + (size_t)CB * NT_ * 2560 <= ws_size) break;
    CB >>= 1;
  }
  char* ws = (char*)d_ws;
  float* adj = (float*)ws;
  unsigned short* wslab = (unsigned short*)(ws + ADJ_BYTES);
  unsigned short* fc1T  = wslab;                        // [256][256]
  unsigned short* wqkT  = wslab + 65536;                // [512][256] (wq|wk)
  unsigned short* wkT   = wslab + 2 * 65536;
  unsigned short* wvT   = wslab + 3 * 65536;
  unsigned short* woT   = wslab + 4 * 65536;
  unsigned short* ff1T  = wslab + 5 * 65536;            // [1024][256]
  unsigned short* ff2T  = wslab + 5 * 65536 + 262144;   // [256][1024]
  float* bqk = (float*)(ws + ADJ_BYTES + 1900544);      // [512] concat bias

  unsigned short* tokb = (unsigned short*)(ws + ADJ_BYTES + WB_BYTES);
  unsigned short* qkb  = tokb + (size_t)CB * NT_ * 256;
  unsigned short* qkv  = qkb + (size_t)CB * NT_ * 256;  // [rows][768] Q|K|V
  unsigned short* ffi  = qkb;                           // [rows][1024] (over qkb+qkv)
  unsigned short* h1b  = tokb;                          // bf16 h1 (over tokb)
  unsigned short* aob  = qkv + 256;                     // pre-LN1 (over K region, ld 768)

  adj_kernel<<<B_, 64, 0, stream>>>(locs, adj);
  convw_kernel<<<256, 256, 0, stream>>>(fc1_w, fc1T, 248, 248, 256, 256);
  convw_kernel<<<256, 256, 0, stream>>>(wq, wqkT, 256, 256, 256, 256);
  convw_kernel<<<256, 256, 0, stream>>>(wk, wkT, 256, 256, 256, 256);
  convw_kernel<<<256, 256, 0, stream>>>(wv, wvT, 256, 256, 256, 256);
  convw_kernel<<<256, 256, 0, stream>>>(wo, woT, 256, 256, 256, 256);
  convw_kernel<<<1024, 256, 0, stream>>>(ff1_w, ff1T, 256, 1024, 256, 1024);
  convw_kernel<<<1024, 256, 0, stream>>>(ff2_w, ff2T, 1024, 256, 1024, 256);
  hipMemcpyAsync(bqk, bq, 256 * sizeof(float), hipMemcpyDeviceToDevice, stream);
  hipMemcpyAsync(bqk + 256, bk, 256 * sizeof(float), hipMemcpyDeviceToDevice, stream);

  for (int b0 = 0; b0 < B_; b0 += CB) {
    const int rows = CB * NT_;        // CB*10752, multiple of 256 (10752=42*256)
    const int MB = rows / 256;
    const float* pos_c = pos_em + (long)b0 * T_ * E_;
    const float* per_c = per_em + (long)b0 * T_ * E_;
    float* out_c = out + (long)b0 * NT_ * E_;
    unsigned short* G = qkv;          // GCN hidden lives in qkv area until consumed

    gcn_kernel<<<CB * T_, 256, 0, stream>>>(x, adj, gcn_w, gcn_b, pos_c, per_c,
                                            G, tokb, qkb, b0);
    // fc1 -> tokb[:,8:256] (+pos) and qkb[:,8:256] (+pos+per)
    {
      dim3 g(MB, 1);
      mfma_gemm<<<g, 512, 0, stream>>>(G, 256, fc1T, 256, 248, fc1_b,
                                       nullptr, tokb, qkb, pos_c, per_c,
                                       nullptr, nullptr, 8, 256, 0);
    }
    // fused Q|K (N=512) from qkb -> qkv[:, 0:512]
    {
      dim3 g(MB, 2);
      mfma_gemm<<<g, 512, 0, stream>>>(qkb, 256, wqkT, 256, 512, bqk,
                                       nullptr, qkv, nullptr, nullptr, nullptr,
                                       nullptr, nullptr, 0, LDQ_, 0);
    }
    // V from tokb -> qkv[:, 512:768]
    {
      dim3 g(MB, 1);
      mfma_gemm<<<g, 512, 0, stream>>>(tokb, 256, wvT, 256, 256, bv,
                                       nullptr, qkv, nullptr, nullptr, nullptr,
                                       nullptr, nullptr, 512, LDQ_, 0);
    }
    // attention (O in-place over Q slice of qkv)
    attn_mfma_kernel<<<CB * N_ * H_, 256, 0, stream>>>(qkv);
    // aob = tokb + O @ wo + bo   (bf16, over dead K region, ld 768)
    {
      dim3 g(MB, 1);
      mfma_gemm<<<g, 512, 0, stream>>>(qkv, LDQ_, woT, 256, 256, bo,
                                       nullptr, aob, nullptr, nullptr, nullptr,
                                       tokb, nullptr, 0, LDQ_, 0);
    }
    // LN1: aob -> h1b (bf16, over tokb)
    ln_bf_kernel<<<rows / 4, 256, 0, stream>>>(aob, LDQ_, ln1_g, ln1_b, h1b, nullptr);
    // FF1: ffi = relu(h1b @ ff1_w + b)
    {
      dim3 g(MB, 4);
      mfma_gemm<<<g, 512, 0, stream>>>(h1b, 256, ff1T, 256, 1024, ff1_b,
                                       nullptr, ffi, nullptr, nullptr, nullptr,
                                       nullptr, nullptr, 0, 1024, 1);
    }
    // FF2: h1b = h1 + ffi @ ff2_w + b  (bf16, element-wise safe aliasing)
    {
      dim3 g(MB, 1);
      mfma_gemm<<<g, 512, 0, stream>>>(ffi, 1024, ff2T, 1024, 256, ff2_b,
                                       nullptr, h1b, nullptr, nullptr, nullptr,
                                       h1b, nullptr, 0, 256, 0);
    }
    // LN2: h1b -> out (f32)
    ln_bf_kernel<<<rows / 4, 256, 0, stream>>>(h1b, 256, ln2_g, ln2_b, nullptr, out_c);
  }
}